// Round 5
// baseline (2218.923 us; speedup 1.0000x reference)
//
#include <hip/hip_runtime.h>
#include <cstdint>
#include <cmath>

#define PARTITIONABLE 1

constexpr int kPH = 12;
constexpr int kB = 16;
constexpr int kH = 256;
constexpr int kZ = 64;
constexpr int kCand = 512;
constexpr int kTopK = 64;
constexpr int kTools = 36;
constexpr int kRT = kB * kCand;   // 8192 rows
constexpr uint32_t kDiscTotal = (uint32_t)kCand * kPH * kB * kTools; // 3538944
constexpr uint32_t kContTotal = (uint32_t)kPH * kB * kCand * 2;      // 196608

constexpr int kRowsB = 16;        // rows per rollout block
constexpr int kStrideB = 20;      // col-major LDS stride (words), 16B-aligned

// ---------------- Threefry-2x32 (JAX-exact: 20 rounds, 5 key injections) ---
__host__ __device__ inline void tf2x32(uint32_t k0, uint32_t k1,
                                       uint32_t x0, uint32_t x1,
                                       uint32_t& o0, uint32_t& o1) {
  uint32_t ks2 = k0 ^ k1 ^ 0x1BD11BDAu;
  x0 += k0; x1 += k1;
#define TFROT(v, d) (((v) << (d)) | ((v) >> (32 - (d))))
#define TFR(r) { x0 += x1; x1 = TFROT(x1, r); x1 ^= x0; }
  TFR(13) TFR(15) TFR(26) TFR(6)
  x0 += k1;  x1 += ks2 + 1u;
  TFR(17) TFR(29) TFR(16) TFR(24)
  x0 += ks2; x1 += k0 + 2u;
  TFR(13) TFR(15) TFR(26) TFR(6)
  x0 += k0;  x1 += k1 + 3u;
  TFR(17) TFR(29) TFR(16) TFR(24)
  x0 += k1;  x1 += ks2 + 4u;
  TFR(13) TFR(15) TFR(26) TFR(6)
  x0 += ks2; x1 += k0 + 5u;
#undef TFR
#undef TFROT
  o0 = x0; o1 = x1;
}

__device__ inline uint32_t jax_bits32(uint32_t k0, uint32_t k1,
                                      uint32_t idx, uint32_t total) {
#if PARTITIONABLE
  (void)total;
  uint32_t y0, y1;
  tf2x32(k0, k1, 0u, idx, y0, y1);
  return y0 ^ y1;
#else
  uint32_t half = total >> 1;
  uint32_t y0, y1;
  if (idx < half) { tf2x32(k0, k1, idx, idx + half, y0, y1); return y0; }
  else            { tf2x32(k0, k1, idx - half, idx, y0, y1); return y1; }
#endif
}

static void host_split3(uint32_t k0, uint32_t k1, uint32_t out[3][2]) {
#if PARTITIONABLE
  for (uint32_t i = 0; i < 3; ++i)
    tf2x32(k0, k1, 0u, i, out[i][0], out[i][1]);
#else
  uint32_t a0,a1,b0,b1,c0,c1;
  tf2x32(k0, k1, 0u, 3u, a0, a1);
  tf2x32(k0, k1, 1u, 4u, b0, b1);
  tf2x32(k0, k1, 2u, 5u, c0, c1);
  out[0][0]=a0; out[0][1]=b0;
  out[1][0]=c0; out[1][1]=a1;
  out[2][0]=b1; out[2][1]=c1;
#endif
}

// ---------------- XLA f32 erf_inv (Giles polynomial) -----------------------
__device__ inline float erfinv_xla(float x) {
  float xx = x * x;
  float w = -(float)log1p((double)(-xx));
  float p;
  if (w < 5.0f) {
    float ww = w - 2.5f;
    p = 2.81022636e-08f;
    p = fmaf(p, ww, 3.43273939e-07f);
    p = fmaf(p, ww, -3.5233877e-06f);
    p = fmaf(p, ww, -4.39150654e-06f);
    p = fmaf(p, ww, 0.00021858087f);
    p = fmaf(p, ww, -0.00125372503f);
    p = fmaf(p, ww, -0.00417768164f);
    p = fmaf(p, ww, 0.246640727f);
    p = fmaf(p, ww, 1.50140941f);
  } else {
    float ww = sqrtf(w) - 3.0f;
    p = -0.000200214257f;
    p = fmaf(p, ww, 0.000100950558f);
    p = fmaf(p, ww, 0.00134934322f);
    p = fmaf(p, ww, -0.00367342844f);
    p = fmaf(p, ww, 0.00573950773f);
    p = fmaf(p, ww, -0.0076224613f);
    p = fmaf(p, ww, 0.00943887047f);
    p = fmaf(p, ww, 1.00167406f);
    p = fmaf(p, ww, 2.83297682f);
  }
  return p * x;
}

// ---------------- categorical sampling (disc actions) ----------------------
__global__ __launch_bounds__(256) void k_sample_disc(
    uint32_t kd0, uint32_t kd1, const float* __restrict__ lfreq,
    float* __restrict__ discA, int it0) {
  int gid = blockIdx.x * 256 + threadIdx.x;   // gid = c*(PH*B) + j
  if (gid >= kCand * kPH * kB) return;
  int c = gid / (kPH * kB);
  int j = gid - c * (kPH * kB);               // j = ph*16 + b
  int best = 0;
  if (it0) {
    uint32_t bm = 0u;
    for (int t = 0; t < kTools; ++t) {
      uint32_t bits = jax_bits32(kd0, kd1, (uint32_t)(gid * kTools + t), kDiscTotal);
      uint32_t m = bits >> 9;
      if (t == 0 || m > bm) { bm = m; best = t; }
    }
  } else {
    const float* lf = lfreq + j * kTools;
    float bv = 0.0f;
    for (int t = 0; t < kTools; ++t) {
      uint32_t bits = jax_bits32(kd0, kd1, (uint32_t)(gid * kTools + t), kDiscTotal);
      float u = __uint_as_float((bits >> 9) | 0x3F800000u) - 1.0f;
      if (u == 0.0f) u = 1.17549435e-38f;
      float l1 = (float)log((double)u);
      float g = -(float)log((double)(-l1));
      float val = g + lf[t];
      if (t == 0 || val > bv) { bv = val; best = t; }
    }
  }
  int ph = j >> 4, b = j & 15;
  discA[ph * kRT + b * kCand + c] = (float)best;
}

// ---------------- normal sampling (cont actions) ---------------------------
__global__ __launch_bounds__(256) void k_sample_cont(
    uint32_t kn0, uint32_t kn1, const float* __restrict__ meanv,
    const float* __restrict__ stdv, float* __restrict__ contA, int it0) {
  int gid = blockIdx.x * 256 + threadIdx.x;
  if (gid >= (int)kContTotal) return;
  uint32_t bits = jax_bits32(kn0, kn1, (uint32_t)gid, kContTotal);
  float f = __uint_as_float((bits >> 9) | 0x3F800000u) - 1.0f;
  const float lo = -0.99999994f;
  float u = fmaxf(lo, f * 2.0f + lo);
  float n = __uint_as_float(0x3FB504F3u) * erfinv_xla(u);
  int d = gid & 1;
  int c = (gid >> 1) & (kCand - 1);
  int rest = gid >> 10;                        // ph*16 + b
  int ph = rest >> 4, b = rest & 15;
  float m, s;
  if (it0) { m = 0.0f; s = 1.0f; }
  else {
    m = meanv[rest * 2 + d];
    s = stdv[rest * 2 + d];
  }
  float x = m + s * n;
  x = fminf(fmaxf(x, -1.0f), 1.0f);
  contA[(ph * kRT + b * kCand + c) * 2 + d] = x;
}

// ---------------- fused 12-step rollout ------------------------------------
// 512 blocks x 16 rows x 128 threads (2 waves). Thread tile: 4 rows x 8 cols,
// FULL k=256 (no partials, no imbalance). Per k: 1 broadcast ds_read_b128 +
// 2 global float4 (L2, lane-duplicated -> coalesced) + 32 FMA. LDS pipe and
// VALU pipe are balanced (~0.75 ratio). 2 barriers/step. Returns in regs.
__global__ __launch_bounds__(128) void k_rollout(
    const float* __restrict__ belief,
    const float* __restrict__ discA, const float* __restrict__ contA,
    const float* __restrict__ Wb, const float* __restrict__ Wa,
    const float* __restrict__ bbv_, const float* __restrict__ Ws,
    const float* __restrict__ bs_, const float* __restrict__ wrb,
    const float* __restrict__ wrs, float* __restrict__ ret) {
  __shared__ float sBc[kH * kStrideB];        // 20 KB col-major belief [k][r]
  __shared__ float sAD[kPH][kRowsB];
  __shared__ float sA0[kPH][kRowsB];
  __shared__ float sA1[kPH][kRowsB];
  __shared__ float sret[kRowsB];

  const int tid = threadIdx.x;
  const int row0 = blockIdx.x * kRowsB;
  const int batch = row0 >> 9;

  const int wave = tid >> 6;
  const int lane = tid & 63;
  const int rg = lane & 3;          // row group (rg minor: lanes 0-3 share cg)
  const int cg = lane >> 2;         // 0..15
  const int r0 = rg * 4;            // rows r0..r0+3
  const int c0 = wave * 128 + cg * 8;   // cols c0..c0+7
  const int zc = wave * 32 + cg * 2;    // z cols zc, zc+1

  // loop-invariant per-thread parameters (8 cols)
  const float4 bbA  = *reinterpret_cast<const float4*>(&bbv_[c0]);
  const float4 bbB  = *reinterpret_cast<const float4*>(&bbv_[c0 + 4]);
  const float4 wa0A = *reinterpret_cast<const float4*>(&Wa[c0]);
  const float4 wa0B = *reinterpret_cast<const float4*>(&Wa[c0 + 4]);
  const float4 wa1A = *reinterpret_cast<const float4*>(&Wa[kH + c0]);
  const float4 wa1B = *reinterpret_cast<const float4*>(&Wa[kH + c0 + 4]);
  const float4 wa2A = *reinterpret_cast<const float4*>(&Wa[2 * kH + c0]);
  const float4 wa2B = *reinterpret_cast<const float4*>(&Wa[2 * kH + c0 + 4]);
  const float4 wrbA = *reinterpret_cast<const float4*>(&wrb[c0]);
  const float4 wrbB = *reinterpret_cast<const float4*>(&wrb[c0 + 4]);
  const float2 bs2  = *reinterpret_cast<const float2*>(&bs_[zc]);
  const float2 wrs2 = *reinterpret_cast<const float2*>(&wrs[zc]);

  // stage belief col-major, replicated across the 16 rows
  for (int c = tid; c < kH; c += 128) {
    float v = belief[batch * kH + c];
    #pragma unroll
    for (int r = 0; r < kRowsB; ++r) sBc[c * kStrideB + r] = v;
  }
  // stage all 12 steps of actions
  for (int i = tid; i < kPH * kRowsB; i += 128) {
    int ph = i >> 4, r = i & 15;
    int gr = row0 + r;
    sAD[ph][r] = discA[ph * kRT + gr];
    sA0[ph][r] = contA[(ph * kRT + gr) * 2 + 0];
    sA1[ph][r] = contA[(ph * kRT + gr) * 2 + 1];
  }
  if (tid < kRowsB) sret[tid] = 0.0f;

  float rsum[4] = {0.0f, 0.0f, 0.0f, 0.0f};
  __syncthreads();

  const float* bK = sBc + r0;                     // LDS read base
  const float* wB = Wb + c0;                      // global Wb base (L2)
  const float* wS = Ws + zc;                      // global Ws base (L2)

  #pragma unroll 1
  for (int ph = 0; ph < kPH; ++ph) {
    // ---- b' = tanh(b @ Wb + a @ Wa + bb), full k per thread ----
    float acc[4][8];
    #pragma unroll
    for (int r = 0; r < 4; ++r)
      #pragma unroll
      for (int c = 0; c < 8; ++c) acc[r][c] = 0.0f;

    #pragma unroll 4
    for (int k = 0; k < kH; ++k) {
      float4 bv = *reinterpret_cast<const float4*>(bK + k * kStrideB);
      float4 w0 = *reinterpret_cast<const float4*>(wB + (size_t)k * kH);
      float4 w1 = *reinterpret_cast<const float4*>(wB + (size_t)k * kH + 4);
      float bvr[4] = {bv.x, bv.y, bv.z, bv.w};
      float wvc[8] = {w0.x, w0.y, w0.z, w0.w, w1.x, w1.y, w1.z, w1.w};
      #pragma unroll
      for (int r = 0; r < 4; ++r)
        #pragma unroll
        for (int c = 0; c < 8; ++c)
          acc[r][c] = fmaf(bvr[r], wvc[c], acc[r][c]);
    }

    // finalize in registers (no LDS partials needed: full k)
    float bn[4][8];
    {
      float bbv[8]  = {bbA.x, bbA.y, bbA.z, bbA.w, bbB.x, bbB.y, bbB.z, bbB.w};
      float wa0v[8] = {wa0A.x, wa0A.y, wa0A.z, wa0A.w, wa0B.x, wa0B.y, wa0B.z, wa0B.w};
      float wa1v[8] = {wa1A.x, wa1A.y, wa1A.z, wa1A.w, wa1B.x, wa1B.y, wa1B.z, wa1B.w};
      float wa2v[8] = {wa2A.x, wa2A.y, wa2A.z, wa2A.w, wa2B.x, wa2B.y, wa2B.z, wa2B.w};
      #pragma unroll
      for (int r = 0; r < 4; ++r) {
        float aD = sAD[ph][r0 + r];
        float a0 = sA0[ph][r0 + r];
        float a1 = sA1[ph][r0 + r];
        #pragma unroll
        for (int c = 0; c < 8; ++c) {
          float t = acc[r][c] + bbv[c] + aD * wa0v[c] + a0 * wa1v[c] + a1 * wa2v[c];
          bn[r][c] = tanhf(t);
        }
      }
      // returns: belief part
      float wrbv[8] = {wrbA.x, wrbA.y, wrbA.z, wrbA.w, wrbB.x, wrbB.y, wrbB.z, wrbB.w};
      #pragma unroll
      for (int r = 0; r < 4; ++r)
        #pragma unroll
        for (int c = 0; c < 8; ++c)
          rsum[r] = fmaf(bn[r][c], wrbv[c], rsum[r]);
    }
    __syncthreads();                 // (1) all waves done reading old sBc

    // write b' col-major
    #pragma unroll
    for (int c = 0; c < 8; ++c)
      *reinterpret_cast<float4*>(&sBc[(c0 + c) * kStrideB + r0]) =
          make_float4(bn[0][c], bn[1][c], bn[2][c], bn[3][c]);
    __syncthreads();                 // (2) new belief visible

    // ---- s = tanh(b' @ Ws + bs), full k; s stays in registers ----
    float sa[4][2] = {{0.0f,0.0f},{0.0f,0.0f},{0.0f,0.0f},{0.0f,0.0f}};
    #pragma unroll 4
    for (int k = 0; k < kH; ++k) {
      float4 bv = *reinterpret_cast<const float4*>(bK + k * kStrideB);
      float2 wv = *reinterpret_cast<const float2*>(wS + (size_t)k * kZ);
      float bvr[4] = {bv.x, bv.y, bv.z, bv.w};
      #pragma unroll
      for (int r = 0; r < 4; ++r) {
        sa[r][0] = fmaf(bvr[r], wv.x, sa[r][0]);
        sa[r][1] = fmaf(bvr[r], wv.y, sa[r][1]);
      }
    }
    #pragma unroll
    for (int r = 0; r < 4; ++r) {
      float s0 = tanhf(sa[r][0] + bs2.x);
      float s1 = tanhf(sa[r][1] + bs2.y);
      rsum[r] = fmaf(s0, wrs2.x, rsum[r]);
      rsum[r] = fmaf(s1, wrs2.y, rsum[r]);
    }
    // no barrier here: next step's first sBc write is after its barrier (1)
  }

  // reduce rsum over cg lanes (xor masks 4..32), then across the 2 waves
  #pragma unroll
  for (int r = 0; r < 4; ++r) {
    float v = rsum[r];
    v += __shfl_xor(v, 4, 64);
    v += __shfl_xor(v, 8, 64);
    v += __shfl_xor(v, 16, 64);
    v += __shfl_xor(v, 32, 64);
    if (cg == 0) atomicAdd(&sret[r0 + r], v);
  }
  __syncthreads();
  if (tid < kRowsB) ret[row0 + tid] = sret[tid];
}

// ---------------- per-batch top-k + statistics -----------------------------
__global__ __launch_bounds__(256) void k_topk_stats(
    const float* __restrict__ ret, const float* __restrict__ discA,
    const float* __restrict__ contA, float* __restrict__ freq,
    float* __restrict__ lfreq, float* __restrict__ meanv,
    float* __restrict__ stdv) {
  __shared__ float rv[kCand];
  __shared__ int selc[kTopK];
  __shared__ int hist[kTools];
  const int b = blockIdx.x, tid = threadIdx.x;
  for (int i = tid; i < kCand; i += 256) rv[i] = ret[b * kCand + i];
  __syncthreads();
  for (int c = tid; c < kCand; c += 256) {
    float v = rv[c];
    int rank = 0;
    for (int o = 0; o < kCand; ++o) {
      float vo = rv[o];
      rank += ((vo > v) || (vo == v && o < c)) ? 1 : 0;
    }
    if (rank < kTopK) selc[rank] = c;
  }
  __syncthreads();
  for (int ph = 0; ph < kPH; ++ph) {
    if (tid < kTools) hist[tid] = 0;
    __syncthreads();
    if (tid < kTopK) {
      int c = selc[tid];
      int idx = ph * kRT + b * kCand + c;
      int d = (int)discA[idx];
      atomicAdd(&hist[d], 1);
      float c0 = contA[idx * 2 + 0];
      float c1 = contA[idx * 2 + 1];
      float s0 = c0, s1 = c1;
      #pragma unroll
      for (int sh = 1; sh < 64; sh <<= 1) {
        s0 += __shfl_xor(s0, sh, 64);
        s1 += __shfl_xor(s1, sh, 64);
      }
      float m0 = s0 * (1.0f / 64.0f);
      float m1 = s1 * (1.0f / 64.0f);
      float d0 = c0 - m0, d1 = c1 - m1;
      float q0 = d0 * d0, q1 = d1 * d1;
      #pragma unroll
      for (int sh = 1; sh < 64; sh <<= 1) {
        q0 += __shfl_xor(q0, sh, 64);
        q1 += __shfl_xor(q1, sh, 64);
      }
      if (tid == 0) {
        int o = (ph * kB + b) * 2;
        meanv[o + 0] = m0;
        meanv[o + 1] = m1;
        stdv[o + 0] = sqrtf(q0 * (1.0f / 64.0f));
        stdv[o + 1] = sqrtf(q1 * (1.0f / 64.0f));
      }
    }
    __syncthreads();
    if (tid < kTools) {
      float fq = (float)(hist[tid] + 1) / 100.0f;
      int o = (ph * kB + b) * kTools + tid;
      freq[o] = fq;
      lfreq[o] = (float)log((double)fq);
    }
    __syncthreads();
  }
}

// ---------------- final output ---------------------------------------------
__global__ void k_final(const float* __restrict__ freq,
                        const float* __restrict__ meanv,
                        float* __restrict__ out) {
  int b = threadIdx.x;
  if (b < kB) {
    const float* f = freq + b * kTools;   // ph = 0
    int best = 0; float bv = f[0];
    for (int t = 1; t < kTools; ++t)
      if (f[t] > bv) { bv = f[t]; best = t; }
    out[b * 3 + 0] = (float)best;
    out[b * 3 + 1] = meanv[b * 2 + 0];
    out[b * 3 + 2] = meanv[b * 2 + 1];
  }
}

extern "C" void kernel_launch(void* const* d_in, const int* in_sizes, int n_in,
                              void* d_out, int out_size, void* d_ws, size_t ws_size,
                              hipStream_t stream) {
  (void)in_sizes; (void)n_in; (void)out_size; (void)ws_size;
  const float* belief = (const float*)d_in[0];
  const float* Wb  = (const float*)d_in[2];
  const float* Wa  = (const float*)d_in[3];
  const float* bb  = (const float*)d_in[4];
  const float* Ws  = (const float*)d_in[5];
  const float* bs  = (const float*)d_in[6];
  const float* wrb = (const float*)d_in[7];
  const float* wrs = (const float*)d_in[8];
  float* out = (float*)d_out;

  float* w = (float*)d_ws;
  float* discA = w;                          // PH*RT
  float* contA = discA + kPH * kRT;          // PH*RT*2
  float* ret   = contA + kPH * kRT * 2;      // RT
  float* freq  = ret + kRT;                  // PH*B*NTOOLS
  float* lfreq = freq + kPH * kB * kTools;   // PH*B*NTOOLS
  float* meanv = lfreq + kPH * kB * kTools;  // PH*B*2
  float* stdv  = meanv + kPH * kB * 2;       // PH*B*2

  uint32_t key0 = 0u, key1 = 42u;            // jax.random.key(42)
  for (int it = 0; it < 3; ++it) {
    uint32_t ks[3][2];
    host_split3(key0, key1, ks);
    int it0 = (it == 0) ? 1 : 0;
    k_sample_disc<<<dim3((kCand * kPH * kB + 255) / 256), dim3(256), 0, stream>>>(
        ks[0][0], ks[0][1], lfreq, discA, it0);
    k_sample_cont<<<dim3((kContTotal + 255) / 256), dim3(256), 0, stream>>>(
        ks[1][0], ks[1][1], meanv, stdv, contA, it0);
    k_rollout<<<dim3(kRT / kRowsB), dim3(128), 0, stream>>>(
        belief, discA, contA, Wb, Wa, bb, Ws, bs, wrb, wrs, ret);
    k_topk_stats<<<dim3(kB), dim3(256), 0, stream>>>(
        ret, discA, contA, freq, lfreq, meanv, stdv);
    key0 = ks[2][0]; key1 = ks[2][1];
  }
  k_final<<<dim3(1), dim3(64), 0, stream>>>(freq, meanv, out);
}

// Round 6
// 1639.003 us; speedup vs baseline: 1.3538x; 1.3538x over previous
//
#include <hip/hip_runtime.h>
#include <cstdint>
#include <cmath>

#define PARTITIONABLE 1

constexpr int kPH = 12;
constexpr int kB = 16;
constexpr int kH = 256;
constexpr int kZ = 64;
constexpr int kCand = 512;
constexpr int kTopK = 64;
constexpr int kTools = 36;
constexpr int kRT = kB * kCand;   // 8192 rows
constexpr uint32_t kDiscTotal = (uint32_t)kCand * kPH * kB * kTools; // 3538944
constexpr uint32_t kContTotal = (uint32_t)kPH * kB * kCand * 2;      // 196608

constexpr int kRowsB = 16;        // rows per rollout block
constexpr int kSB = 20;           // sBc col-major stride (words)
constexpr int kSP = 260;          // pT row stride (words)
constexpr int kSS = 68;           // sPT row stride (words)

// ---------------- Threefry-2x32 (JAX-exact: 20 rounds, 5 key injections) ---
__host__ __device__ inline void tf2x32(uint32_t k0, uint32_t k1,
                                       uint32_t x0, uint32_t x1,
                                       uint32_t& o0, uint32_t& o1) {
  uint32_t ks2 = k0 ^ k1 ^ 0x1BD11BDAu;
  x0 += k0; x1 += k1;
#define TFROT(v, d) (((v) << (d)) | ((v) >> (32 - (d))))
#define TFR(r) { x0 += x1; x1 = TFROT(x1, r); x1 ^= x0; }
  TFR(13) TFR(15) TFR(26) TFR(6)
  x0 += k1;  x1 += ks2 + 1u;
  TFR(17) TFR(29) TFR(16) TFR(24)
  x0 += ks2; x1 += k0 + 2u;
  TFR(13) TFR(15) TFR(26) TFR(6)
  x0 += k0;  x1 += k1 + 3u;
  TFR(17) TFR(29) TFR(16) TFR(24)
  x0 += k1;  x1 += ks2 + 4u;
  TFR(13) TFR(15) TFR(26) TFR(6)
  x0 += ks2; x1 += k0 + 5u;
#undef TFR
#undef TFROT
  o0 = x0; o1 = x1;
}

__device__ inline uint32_t jax_bits32(uint32_t k0, uint32_t k1,
                                      uint32_t idx, uint32_t total) {
#if PARTITIONABLE
  (void)total;
  uint32_t y0, y1;
  tf2x32(k0, k1, 0u, idx, y0, y1);
  return y0 ^ y1;
#else
  uint32_t half = total >> 1;
  uint32_t y0, y1;
  if (idx < half) { tf2x32(k0, k1, idx, idx + half, y0, y1); return y0; }
  else            { tf2x32(k0, k1, idx - half, idx, y0, y1); return y1; }
#endif
}

static void host_split3(uint32_t k0, uint32_t k1, uint32_t out[3][2]) {
#if PARTITIONABLE
  for (uint32_t i = 0; i < 3; ++i)
    tf2x32(k0, k1, 0u, i, out[i][0], out[i][1]);
#else
  uint32_t a0,a1,b0,b1,c0,c1;
  tf2x32(k0, k1, 0u, 3u, a0, a1);
  tf2x32(k0, k1, 1u, 4u, b0, b1);
  tf2x32(k0, k1, 2u, 5u, c0, c1);
  out[0][0]=a0; out[0][1]=b0;
  out[1][0]=c0; out[1][1]=a1;
  out[2][0]=b1; out[2][1]=c1;
#endif
}

// ---------------- XLA f32 erf_inv (Giles polynomial) -----------------------
__device__ inline float erfinv_xla(float x) {
  float xx = x * x;
  float w = -(float)log1p((double)(-xx));
  float p;
  if (w < 5.0f) {
    float ww = w - 2.5f;
    p = 2.81022636e-08f;
    p = fmaf(p, ww, 3.43273939e-07f);
    p = fmaf(p, ww, -3.5233877e-06f);
    p = fmaf(p, ww, -4.39150654e-06f);
    p = fmaf(p, ww, 0.00021858087f);
    p = fmaf(p, ww, -0.00125372503f);
    p = fmaf(p, ww, -0.00417768164f);
    p = fmaf(p, ww, 0.246640727f);
    p = fmaf(p, ww, 1.50140941f);
  } else {
    float ww = sqrtf(w) - 3.0f;
    p = -0.000200214257f;
    p = fmaf(p, ww, 0.000100950558f);
    p = fmaf(p, ww, 0.00134934322f);
    p = fmaf(p, ww, -0.00367342844f);
    p = fmaf(p, ww, 0.00573950773f);
    p = fmaf(p, ww, -0.0076224613f);
    p = fmaf(p, ww, 0.00943887047f);
    p = fmaf(p, ww, 1.00167406f);
    p = fmaf(p, ww, 2.83297682f);
  }
  return p * x;
}

// ---------------- categorical sampling (disc actions) ----------------------
__global__ __launch_bounds__(256) void k_sample_disc(
    uint32_t kd0, uint32_t kd1, const float* __restrict__ lfreq,
    float* __restrict__ discA, int it0) {
  int gid = blockIdx.x * 256 + threadIdx.x;   // gid = c*(PH*B) + j
  if (gid >= kCand * kPH * kB) return;
  int c = gid / (kPH * kB);
  int j = gid - c * (kPH * kB);               // j = ph*16 + b
  int best = 0;
  if (it0) {
    uint32_t bm = 0u;
    for (int t = 0; t < kTools; ++t) {
      uint32_t bits = jax_bits32(kd0, kd1, (uint32_t)(gid * kTools + t), kDiscTotal);
      uint32_t m = bits >> 9;
      if (t == 0 || m > bm) { bm = m; best = t; }
    }
  } else {
    const float* lf = lfreq + j * kTools;
    float bv = 0.0f;
    for (int t = 0; t < kTools; ++t) {
      uint32_t bits = jax_bits32(kd0, kd1, (uint32_t)(gid * kTools + t), kDiscTotal);
      float u = __uint_as_float((bits >> 9) | 0x3F800000u) - 1.0f;
      if (u == 0.0f) u = 1.17549435e-38f;
      float l1 = (float)log((double)u);
      float g = -(float)log((double)(-l1));
      float val = g + lf[t];
      if (t == 0 || val > bv) { bv = val; best = t; }
    }
  }
  int ph = j >> 4, b = j & 15;
  discA[ph * kRT + b * kCand + c] = (float)best;
}

// ---------------- normal sampling (cont actions) ---------------------------
__global__ __launch_bounds__(256) void k_sample_cont(
    uint32_t kn0, uint32_t kn1, const float* __restrict__ meanv,
    const float* __restrict__ stdv, float* __restrict__ contA, int it0) {
  int gid = blockIdx.x * 256 + threadIdx.x;
  if (gid >= (int)kContTotal) return;
  uint32_t bits = jax_bits32(kn0, kn1, (uint32_t)gid, kContTotal);
  float f = __uint_as_float((bits >> 9) | 0x3F800000u) - 1.0f;
  const float lo = -0.99999994f;
  float u = fmaxf(lo, f * 2.0f + lo);
  float n = __uint_as_float(0x3FB504F3u) * erfinv_xla(u);
  int d = gid & 1;
  int c = (gid >> 1) & (kCand - 1);
  int rest = gid >> 10;                        // ph*16 + b
  int ph = rest >> 4, b = rest & 15;
  float m, s;
  if (it0) { m = 0.0f; s = 1.0f; }
  else {
    m = meanv[rest * 2 + d];
    s = stdv[rest * 2 + d];
  }
  float x = m + s * n;
  x = fminf(fmaxf(x, -1.0f), 1.0f);
  contA[(ph * kRT + b * kCand + c) * 2 + d] = x;
}

// ---------------- fused 12-step rollout ------------------------------------
// 512 blocks x 16 rows x 512 threads (8 waves; 2 blocks/CU = 4 waves/SIMD).
// b-phase: k-split-2, thread tile 2 rows x 8 cols: per k 1 ds_read_b64
// (broadcast) + 2 global float4 (L2) + 16 FMA -> FMA-bound with 4x TLP.
// s-phase: k-split-4, thread tile 2 rows x 4 z. Deterministic reductions
// (LDS partials in fixed order, no fp32 atomics). 3 barriers/step.
__global__ __launch_bounds__(512, 4) void k_rollout(
    const float* __restrict__ belief,
    const float* __restrict__ discA, const float* __restrict__ contA,
    const float* __restrict__ Wb, const float* __restrict__ Wa,
    const float* __restrict__ bbv_, const float* __restrict__ Ws,
    const float* __restrict__ bs_, const float* __restrict__ wrb,
    const float* __restrict__ wrs, float* __restrict__ ret) {
  __shared__ float sBc[kH * kSB];             // 20 KB col-major belief [k][r]
  __shared__ float pT[kRowsB * kSP];          // 16.6 KB b-partials (kw1)
  __shared__ float sPT[3][kRowsB][kSS];       // 13 KB s-partials (q1..q3)
  __shared__ float sAD[kPH][kRowsB];
  __shared__ float sA0[kPH][kRowsB];
  __shared__ float sA1[kPH][kRowsB];
  __shared__ float sretP[8][kRowsB];

  const int tid = threadIdx.x;
  const int row0 = blockIdx.x * kRowsB;
  const int batch = row0 >> 9;

  // b-phase mapping: k-half kw, rows 2rg..+1, cols 8cg..+7
  const int kw = tid >> 8;
  const int t8 = tid & 255;
  const int rg = t8 & 7;
  const int cg = t8 >> 3;            // 0..31
  const int r0 = rg * 2;
  const int c0 = cg * 8;
  const int kb = kw * 128;

  // s-phase mapping: k-quarter sq, rows 2srg..+1, z cols 4szg..+3
  const int sq = tid >> 7;           // 0..3
  const int t7 = tid & 127;
  const int srg = t7 & 7;
  const int szg = t7 >> 3;           // 0..15
  const int sr0 = srg * 2;
  const int sz0 = szg * 4;
  const int skb = sq * 64;

  // loop-invariant params
  const float4 bbA  = *reinterpret_cast<const float4*>(&bbv_[c0]);
  const float4 bbB  = *reinterpret_cast<const float4*>(&bbv_[c0 + 4]);
  const float4 wa0A = *reinterpret_cast<const float4*>(&Wa[c0]);
  const float4 wa0B = *reinterpret_cast<const float4*>(&Wa[c0 + 4]);
  const float4 wa1A = *reinterpret_cast<const float4*>(&Wa[kH + c0]);
  const float4 wa1B = *reinterpret_cast<const float4*>(&Wa[kH + c0 + 4]);
  const float4 wa2A = *reinterpret_cast<const float4*>(&Wa[2 * kH + c0]);
  const float4 wa2B = *reinterpret_cast<const float4*>(&Wa[2 * kH + c0 + 4]);
  const float4 wrbA = *reinterpret_cast<const float4*>(&wrb[c0]);
  const float4 wrbB = *reinterpret_cast<const float4*>(&wrb[c0 + 4]);
  const float4 bs4  = *reinterpret_cast<const float4*>(&bs_[sz0]);
  const float4 wrs4 = *reinterpret_cast<const float4*>(&wrs[sz0]);

  // stage belief col-major (replicated across the block's 16 rows)
  if (tid < kH) {
    float v = belief[batch * kH + tid];
    float2 vv = make_float2(v, v);
    #pragma unroll
    for (int r = 0; r < kRowsB; r += 2)
      *reinterpret_cast<float2*>(&sBc[tid * kSB + r]) = vv;
  }
  // stage all 12 steps of actions
  for (int i = tid; i < kPH * kRowsB; i += 512) {
    int ph = i >> 4, r = i & 15;
    int gr = row0 + r;
    sAD[ph][r] = discA[ph * kRT + gr];
    sA0[ph][r] = contA[(ph * kRT + gr) * 2 + 0];
    sA1[ph][r] = contA[(ph * kRT + gr) * 2 + 1];
  }

  float rsum[2] = {0.0f, 0.0f};
  float ssum[2] = {0.0f, 0.0f};
  __syncthreads();

  const float* bP = sBc + kb * kSB + r0;           // LDS b-read base
  const float* wP = Wb + (size_t)kb * kH + c0;     // global Wb base (L2)
  const float* bS = sBc + skb * kSB + sr0;         // LDS s-read base
  const float* wS = Ws + (size_t)skb * kZ + sz0;   // global Ws base (L2)

  #pragma unroll 1
  for (int ph = 0; ph < kPH; ++ph) {
    // ---- b' partials: 2x8 tile over this thread's k-half ----
    float acc[2][8];
    #pragma unroll
    for (int r = 0; r < 2; ++r)
      #pragma unroll
      for (int c = 0; c < 8; ++c) acc[r][c] = 0.0f;

    #pragma unroll 4
    for (int k = 0; k < 128; ++k) {
      float2 bv = *reinterpret_cast<const float2*>(bP + k * kSB);
      float4 w0 = *reinterpret_cast<const float4*>(wP + (size_t)k * kH);
      float4 w1 = *reinterpret_cast<const float4*>(wP + (size_t)k * kH + 4);
      acc[0][0] = fmaf(bv.x, w0.x, acc[0][0]);
      acc[0][1] = fmaf(bv.x, w0.y, acc[0][1]);
      acc[0][2] = fmaf(bv.x, w0.z, acc[0][2]);
      acc[0][3] = fmaf(bv.x, w0.w, acc[0][3]);
      acc[0][4] = fmaf(bv.x, w1.x, acc[0][4]);
      acc[0][5] = fmaf(bv.x, w1.y, acc[0][5]);
      acc[0][6] = fmaf(bv.x, w1.z, acc[0][6]);
      acc[0][7] = fmaf(bv.x, w1.w, acc[0][7]);
      acc[1][0] = fmaf(bv.y, w0.x, acc[1][0]);
      acc[1][1] = fmaf(bv.y, w0.y, acc[1][1]);
      acc[1][2] = fmaf(bv.y, w0.z, acc[1][2]);
      acc[1][3] = fmaf(bv.y, w0.w, acc[1][3]);
      acc[1][4] = fmaf(bv.y, w1.x, acc[1][4]);
      acc[1][5] = fmaf(bv.y, w1.y, acc[1][5]);
      acc[1][6] = fmaf(bv.y, w1.z, acc[1][6]);
      acc[1][7] = fmaf(bv.y, w1.w, acc[1][7]);
    }
    if (kw == 1) {
      *reinterpret_cast<float4*>(&pT[r0 * kSP + c0]) =
          make_float4(acc[0][0], acc[0][1], acc[0][2], acc[0][3]);
      *reinterpret_cast<float4*>(&pT[r0 * kSP + c0 + 4]) =
          make_float4(acc[0][4], acc[0][5], acc[0][6], acc[0][7]);
      *reinterpret_cast<float4*>(&pT[(r0 + 1) * kSP + c0]) =
          make_float4(acc[1][0], acc[1][1], acc[1][2], acc[1][3]);
      *reinterpret_cast<float4*>(&pT[(r0 + 1) * kSP + c0 + 4]) =
          make_float4(acc[1][4], acc[1][5], acc[1][6], acc[1][7]);
    }
    __syncthreads();                          // (1) pT ready; old sBc free

    if (kw == 0) {
      float bbv[8]  = {bbA.x, bbA.y, bbA.z, bbA.w, bbB.x, bbB.y, bbB.z, bbB.w};
      float wa0v[8] = {wa0A.x, wa0A.y, wa0A.z, wa0A.w, wa0B.x, wa0B.y, wa0B.z, wa0B.w};
      float wa1v[8] = {wa1A.x, wa1A.y, wa1A.z, wa1A.w, wa1B.x, wa1B.y, wa1B.z, wa1B.w};
      float wa2v[8] = {wa2A.x, wa2A.y, wa2A.z, wa2A.w, wa2B.x, wa2B.y, wa2B.z, wa2B.w};
      float wrbv[8] = {wrbA.x, wrbA.y, wrbA.z, wrbA.w, wrbB.x, wrbB.y, wrbB.z, wrbB.w};
      float bn[2][8];
      #pragma unroll
      for (int rr = 0; rr < 2; ++rr) {
        float4 p0 = *reinterpret_cast<const float4*>(&pT[(r0 + rr) * kSP + c0]);
        float4 p1 = *reinterpret_cast<const float4*>(&pT[(r0 + rr) * kSP + c0 + 4]);
        float pv[8] = {p0.x, p0.y, p0.z, p0.w, p1.x, p1.y, p1.z, p1.w};
        float aD = sAD[ph][r0 + rr];
        float a0 = sA0[ph][r0 + rr];
        float a1 = sA1[ph][r0 + rr];
        #pragma unroll
        for (int c = 0; c < 8; ++c) {
          float t = acc[rr][c] + pv[c] + bbv[c] + aD * wa0v[c] + a0 * wa1v[c] + a1 * wa2v[c];
          bn[rr][c] = tanhf(t);
          rsum[rr] = fmaf(bn[rr][c], wrbv[c], rsum[rr]);
        }
      }
      // write b' back col-major
      #pragma unroll
      for (int c = 0; c < 8; ++c)
        *reinterpret_cast<float2*>(&sBc[(c0 + c) * kSB + r0]) =
            make_float2(bn[0][c], bn[1][c]);
    }
    __syncthreads();                          // (2) new belief visible

    // ---- s partials: 2x4 tile over this thread's k-quarter ----
    float sa[2][4];
    #pragma unroll
    for (int rr = 0; rr < 2; ++rr)
      #pragma unroll
      for (int z = 0; z < 4; ++z) sa[rr][z] = 0.0f;

    #pragma unroll 4
    for (int k = 0; k < 64; ++k) {
      float2 bv = *reinterpret_cast<const float2*>(bS + k * kSB);
      float4 wv = *reinterpret_cast<const float4*>(wS + (size_t)k * kZ);
      sa[0][0] = fmaf(bv.x, wv.x, sa[0][0]);
      sa[0][1] = fmaf(bv.x, wv.y, sa[0][1]);
      sa[0][2] = fmaf(bv.x, wv.z, sa[0][2]);
      sa[0][3] = fmaf(bv.x, wv.w, sa[0][3]);
      sa[1][0] = fmaf(bv.y, wv.x, sa[1][0]);
      sa[1][1] = fmaf(bv.y, wv.y, sa[1][1]);
      sa[1][2] = fmaf(bv.y, wv.z, sa[1][2]);
      sa[1][3] = fmaf(bv.y, wv.w, sa[1][3]);
    }
    if (sq != 0) {
      *reinterpret_cast<float4*>(&sPT[sq - 1][sr0][sz0]) =
          make_float4(sa[0][0], sa[0][1], sa[0][2], sa[0][3]);
      *reinterpret_cast<float4*>(&sPT[sq - 1][sr0 + 1][sz0]) =
          make_float4(sa[1][0], sa[1][1], sa[1][2], sa[1][3]);
    }
    __syncthreads();                          // (3) s-partials ready

    if (sq == 0) {
      #pragma unroll
      for (int rr = 0; rr < 2; ++rr) {
        float4 p1 = *reinterpret_cast<const float4*>(&sPT[0][sr0 + rr][sz0]);
        float4 p2 = *reinterpret_cast<const float4*>(&sPT[1][sr0 + rr][sz0]);
        float4 p3 = *reinterpret_cast<const float4*>(&sPT[2][sr0 + rr][sz0]);
        float t0 = ((sa[rr][0] + p1.x) + p2.x) + p3.x + bs4.x;
        float t1 = ((sa[rr][1] + p1.y) + p2.y) + p3.y + bs4.y;
        float t2 = ((sa[rr][2] + p1.z) + p2.z) + p3.z + bs4.z;
        float t3 = ((sa[rr][3] + p1.w) + p2.w) + p3.w + bs4.w;
        float s0 = tanhf(t0), s1 = tanhf(t1), s2 = tanhf(t2), s3 = tanhf(t3);
        ssum[rr] = fmaf(s0, wrs4.x, ssum[rr]);
        ssum[rr] = fmaf(s1, wrs4.y, ssum[rr]);
        ssum[rr] = fmaf(s2, wrs4.z, ssum[rr]);
        ssum[rr] = fmaf(s3, wrs4.w, ssum[rr]);
      }
    }
    // no 4th barrier: next step's pT/sPT writes are >=2 barriers away from
    // this step's reads, and sBc is only rewritten after next bar (1).
  }

  // deterministic final reduce: wave-level shuffle, then fixed-order sum
  float v0 = rsum[0] + ssum[0];
  float v1 = rsum[1] + ssum[1];
  v0 += __shfl_xor(v0, 8, 64);
  v0 += __shfl_xor(v0, 16, 64);
  v0 += __shfl_xor(v0, 32, 64);
  v1 += __shfl_xor(v1, 8, 64);
  v1 += __shfl_xor(v1, 16, 64);
  v1 += __shfl_xor(v1, 32, 64);
  const int lane6 = tid & 63;
  const int wv6 = tid >> 6;
  if (lane6 < 8) {
    sretP[wv6][lane6 * 2 + 0] = v0;
    sretP[wv6][lane6 * 2 + 1] = v1;
  }
  __syncthreads();
  if (tid < kRowsB) {
    float s = 0.0f;
    #pragma unroll
    for (int w = 0; w < 8; ++w) s += sretP[w][tid];
    ret[row0 + tid] = s;
  }
}

// ---------------- per-batch top-k + statistics -----------------------------
__global__ __launch_bounds__(256) void k_topk_stats(
    const float* __restrict__ ret, const float* __restrict__ discA,
    const float* __restrict__ contA, float* __restrict__ freq,
    float* __restrict__ lfreq, float* __restrict__ meanv,
    float* __restrict__ stdv) {
  __shared__ float rv[kCand];
  __shared__ int selc[kTopK];
  __shared__ int hist[kTools];
  const int b = blockIdx.x, tid = threadIdx.x;
  for (int i = tid; i < kCand; i += 256) rv[i] = ret[b * kCand + i];
  __syncthreads();
  for (int c = tid; c < kCand; c += 256) {
    float v = rv[c];
    int rank = 0;
    for (int o = 0; o < kCand; ++o) {
      float vo = rv[o];
      rank += ((vo > v) || (vo == v && o < c)) ? 1 : 0;
    }
    if (rank < kTopK) selc[rank] = c;
  }
  __syncthreads();
  for (int ph = 0; ph < kPH; ++ph) {
    if (tid < kTools) hist[tid] = 0;
    __syncthreads();
    if (tid < kTopK) {
      int c = selc[tid];
      int idx = ph * kRT + b * kCand + c;
      int d = (int)discA[idx];
      atomicAdd(&hist[d], 1);
      float c0 = contA[idx * 2 + 0];
      float c1 = contA[idx * 2 + 1];
      float s0 = c0, s1 = c1;
      #pragma unroll
      for (int sh = 1; sh < 64; sh <<= 1) {
        s0 += __shfl_xor(s0, sh, 64);
        s1 += __shfl_xor(s1, sh, 64);
      }
      float m0 = s0 * (1.0f / 64.0f);
      float m1 = s1 * (1.0f / 64.0f);
      float d0 = c0 - m0, d1 = c1 - m1;
      float q0 = d0 * d0, q1 = d1 * d1;
      #pragma unroll
      for (int sh = 1; sh < 64; sh <<= 1) {
        q0 += __shfl_xor(q0, sh, 64);
        q1 += __shfl_xor(q1, sh, 64);
      }
      if (tid == 0) {
        int o = (ph * kB + b) * 2;
        meanv[o + 0] = m0;
        meanv[o + 1] = m1;
        stdv[o + 0] = sqrtf(q0 * (1.0f / 64.0f));
        stdv[o + 1] = sqrtf(q1 * (1.0f / 64.0f));
      }
    }
    __syncthreads();
    if (tid < kTools) {
      float fq = (float)(hist[tid] + 1) / 100.0f;
      int o = (ph * kB + b) * kTools + tid;
      freq[o] = fq;
      lfreq[o] = (float)log((double)fq);
    }
    __syncthreads();
  }
}

// ---------------- final output ---------------------------------------------
__global__ void k_final(const float* __restrict__ freq,
                        const float* __restrict__ meanv,
                        float* __restrict__ out) {
  int b = threadIdx.x;
  if (b < kB) {
    const float* f = freq + b * kTools;   // ph = 0
    int best = 0; float bv = f[0];
    for (int t = 1; t < kTools; ++t)
      if (f[t] > bv) { bv = f[t]; best = t; }
    out[b * 3 + 0] = (float)best;
    out[b * 3 + 1] = meanv[b * 2 + 0];
    out[b * 3 + 2] = meanv[b * 2 + 1];
  }
}

extern "C" void kernel_launch(void* const* d_in, const int* in_sizes, int n_in,
                              void* d_out, int out_size, void* d_ws, size_t ws_size,
                              hipStream_t stream) {
  (void)in_sizes; (void)n_in; (void)out_size; (void)ws_size;
  const float* belief = (const float*)d_in[0];
  const float* Wb  = (const float*)d_in[2];
  const float* Wa  = (const float*)d_in[3];
  const float* bb  = (const float*)d_in[4];
  const float* Ws  = (const float*)d_in[5];
  const float* bs  = (const float*)d_in[6];
  const float* wrb = (const float*)d_in[7];
  const float* wrs = (const float*)d_in[8];
  float* out = (float*)d_out;

  float* w = (float*)d_ws;
  float* discA = w;                          // PH*RT
  float* contA = discA + kPH * kRT;          // PH*RT*2
  float* ret   = contA + kPH * kRT * 2;      // RT
  float* freq  = ret + kRT;                  // PH*B*NTOOLS
  float* lfreq = freq + kPH * kB * kTools;   // PH*B*NTOOLS
  float* meanv = lfreq + kPH * kB * kTools;  // PH*B*2
  float* stdv  = meanv + kPH * kB * 2;       // PH*B*2

  uint32_t key0 = 0u, key1 = 42u;            // jax.random.key(42)
  for (int it = 0; it < 3; ++it) {
    uint32_t ks[3][2];
    host_split3(key0, key1, ks);
    int it0 = (it == 0) ? 1 : 0;
    k_sample_disc<<<dim3((kCand * kPH * kB + 255) / 256), dim3(256), 0, stream>>>(
        ks[0][0], ks[0][1], lfreq, discA, it0);
    k_sample_cont<<<dim3((kContTotal + 255) / 256), dim3(256), 0, stream>>>(
        ks[1][0], ks[1][1], meanv, stdv, contA, it0);
    k_rollout<<<dim3(kRT / kRowsB), dim3(512), 0, stream>>>(
        belief, discA, contA, Wb, Wa, bb, Ws, bs, wrb, wrs, ret);
    k_topk_stats<<<dim3(kB), dim3(256), 0, stream>>>(
        ret, discA, contA, freq, lfreq, meanv, stdv);
    key0 = ks[2][0]; key1 = ks[2][1];
  }
  k_final<<<dim3(1), dim3(64), 0, stream>>>(freq, meanv, out);
}

// Round 8
// 1122.215 us; speedup vs baseline: 1.9773x; 1.4605x over previous
//
#include <hip/hip_runtime.h>
#include <cstdint>
#include <cmath>

#define PARTITIONABLE 1

constexpr int kPH = 12;
constexpr int kB = 16;
constexpr int kH = 256;
constexpr int kZ = 64;
constexpr int kCand = 512;
constexpr int kTopK = 64;
constexpr int kTools = 36;
constexpr int kRT = kB * kCand;   // 8192 rows
constexpr uint32_t kDiscTotal = (uint32_t)kCand * kPH * kB * kTools; // 3538944
constexpr uint32_t kContTotal = (uint32_t)kPH * kB * kCand * 2;      // 196608

constexpr int kRowsB = 16;        // rows per rollout block

// ---------------- Threefry-2x32 (JAX-exact: 20 rounds, 5 key injections) ---
__host__ __device__ inline void tf2x32(uint32_t k0, uint32_t k1,
                                       uint32_t x0, uint32_t x1,
                                       uint32_t& o0, uint32_t& o1) {
  uint32_t ks2 = k0 ^ k1 ^ 0x1BD11BDAu;
  x0 += k0; x1 += k1;
#define TFROT(v, d) (((v) << (d)) | ((v) >> (32 - (d))))
#define TFR(r) { x0 += x1; x1 = TFROT(x1, r); x1 ^= x0; }
  TFR(13) TFR(15) TFR(26) TFR(6)
  x0 += k1;  x1 += ks2 + 1u;
  TFR(17) TFR(29) TFR(16) TFR(24)
  x0 += ks2; x1 += k0 + 2u;
  TFR(13) TFR(15) TFR(26) TFR(6)
  x0 += k0;  x1 += k1 + 3u;
  TFR(17) TFR(29) TFR(16) TFR(24)
  x0 += k1;  x1 += ks2 + 4u;
  TFR(13) TFR(15) TFR(26) TFR(6)
  x0 += ks2; x1 += k0 + 5u;
#undef TFR
#undef TFROT
  o0 = x0; o1 = x1;
}

__device__ inline uint32_t jax_bits32(uint32_t k0, uint32_t k1,
                                      uint32_t idx, uint32_t total) {
#if PARTITIONABLE
  (void)total;
  uint32_t y0, y1;
  tf2x32(k0, k1, 0u, idx, y0, y1);
  return y0 ^ y1;
#else
  uint32_t half = total >> 1;
  uint32_t y0, y1;
  if (idx < half) { tf2x32(k0, k1, idx, idx + half, y0, y1); return y0; }
  else            { tf2x32(k0, k1, idx - half, idx, y0, y1); return y1; }
#endif
}

static void host_split3(uint32_t k0, uint32_t k1, uint32_t out[3][2]) {
#if PARTITIONABLE
  for (uint32_t i = 0; i < 3; ++i)
    tf2x32(k0, k1, 0u, i, out[i][0], out[i][1]);
#else
  uint32_t a0,a1,b0,b1,c0,c1;
  tf2x32(k0, k1, 0u, 3u, a0, a1);
  tf2x32(k0, k1, 1u, 4u, b0, b1);
  tf2x32(k0, k1, 2u, 5u, c0, c1);
  out[0][0]=a0; out[0][1]=b0;
  out[1][0]=c0; out[1][1]=a1;
  out[2][0]=b1; out[2][1]=c1;
#endif
}

// ---------------- XLA f32 erf_inv (Giles polynomial) -----------------------
__device__ inline float erfinv_xla(float x) {
  float xx = x * x;
  float w = -(float)log1p((double)(-xx));
  float p;
  if (w < 5.0f) {
    float ww = w - 2.5f;
    p = 2.81022636e-08f;
    p = fmaf(p, ww, 3.43273939e-07f);
    p = fmaf(p, ww, -3.5233877e-06f);
    p = fmaf(p, ww, -4.39150654e-06f);
    p = fmaf(p, ww, 0.00021858087f);
    p = fmaf(p, ww, -0.00125372503f);
    p = fmaf(p, ww, -0.00417768164f);
    p = fmaf(p, ww, 0.246640727f);
    p = fmaf(p, ww, 1.50140941f);
  } else {
    float ww = sqrtf(w) - 3.0f;
    p = -0.000200214257f;
    p = fmaf(p, ww, 0.000100950558f);
    p = fmaf(p, ww, 0.00134934322f);
    p = fmaf(p, ww, -0.00367342844f);
    p = fmaf(p, ww, 0.00573950773f);
    p = fmaf(p, ww, -0.0076224613f);
    p = fmaf(p, ww, 0.00943887047f);
    p = fmaf(p, ww, 1.00167406f);
    p = fmaf(p, ww, 2.83297682f);
  }
  return p * x;
}

// ---------------- categorical sampling (disc actions) ----------------------
__global__ __launch_bounds__(256) void k_sample_disc(
    uint32_t kd0, uint32_t kd1, const float* __restrict__ lfreq,
    float* __restrict__ discA, int it0) {
  int gid = blockIdx.x * 256 + threadIdx.x;   // gid = c*(PH*B) + j
  if (gid >= kCand * kPH * kB) return;
  int c = gid / (kPH * kB);
  int j = gid - c * (kPH * kB);               // j = ph*16 + b
  int best = 0;
  if (it0) {
    uint32_t bm = 0u;
    for (int t = 0; t < kTools; ++t) {
      uint32_t bits = jax_bits32(kd0, kd1, (uint32_t)(gid * kTools + t), kDiscTotal);
      uint32_t m = bits >> 9;
      if (t == 0 || m > bm) { bm = m; best = t; }
    }
  } else {
    const float* lf = lfreq + j * kTools;
    float bv = 0.0f;
    for (int t = 0; t < kTools; ++t) {
      uint32_t bits = jax_bits32(kd0, kd1, (uint32_t)(gid * kTools + t), kDiscTotal);
      float u = __uint_as_float((bits >> 9) | 0x3F800000u) - 1.0f;
      if (u == 0.0f) u = 1.17549435e-38f;
      float l1 = (float)log((double)u);
      float g = -(float)log((double)(-l1));
      float val = g + lf[t];
      if (t == 0 || val > bv) { bv = val; best = t; }
    }
  }
  int ph = j >> 4, b = j & 15;
  discA[ph * kRT + b * kCand + c] = (float)best;
}

// ---------------- normal sampling (cont actions) ---------------------------
__global__ __launch_bounds__(256) void k_sample_cont(
    uint32_t kn0, uint32_t kn1, const float* __restrict__ meanv,
    const float* __restrict__ stdv, float* __restrict__ contA, int it0) {
  int gid = blockIdx.x * 256 + threadIdx.x;
  if (gid >= (int)kContTotal) return;
  uint32_t bits = jax_bits32(kn0, kn1, (uint32_t)gid, kContTotal);
  float f = __uint_as_float((bits >> 9) | 0x3F800000u) - 1.0f;
  const float lo = -0.99999994f;
  float u = fmaxf(lo, f * 2.0f + lo);
  float n = __uint_as_float(0x3FB504F3u) * erfinv_xla(u);
  int d = gid & 1;
  int c = (gid >> 1) & (kCand - 1);
  int rest = gid >> 10;                        // ph*16 + b
  int ph = rest >> 4, b = rest & 15;
  float m, s;
  if (it0) { m = 0.0f; s = 1.0f; }
  else {
    m = meanv[rest * 2 + d];
    s = stdv[rest * 2 + d];
  }
  float x = m + s * n;
  x = fminf(fmaxf(x, -1.0f), 1.0f);
  contA[(ph * kRT + b * kCand + c) * 2 + d] = x;
}

// ---------------- fused 12-step rollout ------------------------------------
// 512 blocks x 16 rows x 512 threads (8 waves; 2 blocks/CU = 4 waves/SIMD).
// b-phase: wave = (rowg, ks); 64 lanes span all 64 col-groups -> Wb float4
// loads fully coalesced, ZERO lane duplication (1 VMEM instr per 32 FMA).
// Belief reads are wave-uniform-address ds_read_b128 broadcasts. k-split-4
// partials through 3 LDS planes; 2-wave finalize; 3 barriers/step.
// s-phase analog with scalar Ws loads (64 lanes span all 64 z).
__global__ __launch_bounds__(512, 4) void k_rollout(
    const float* __restrict__ belief,
    const float* __restrict__ discA, const float* __restrict__ contA,
    const float* __restrict__ Wb, const float* __restrict__ Wa,
    const float* __restrict__ bbv_, const float* __restrict__ Ws,
    const float* __restrict__ bs_, const float* __restrict__ wrb,
    const float* __restrict__ wrs, float* __restrict__ ret) {
  __shared__ float sBc[kH * kRowsB];          // 16 KB, [k][r] (stride 16)
  __shared__ float pT[3][kRowsB][kH];         // 48 KB  b-partials (ks 1..3)
  __shared__ float sPT[3][kRowsB][kZ];        // 12 KB  s-partials (sks 1..3)
  __shared__ float sAD[kPH][kRowsB];
  __shared__ float sA0[kPH][kRowsB];
  __shared__ float sA1[kPH][kRowsB];

  const int tid = threadIdx.x;
  const int row0 = blockIdx.x * kRowsB;
  const int batch = row0 >> 9;

  // b-phase mapping: wave w -> rowg = w&1, ks = w>>1; lane = colg
  const int w = tid >> 6;
  const int lane = tid & 63;
  const int rowg = w & 1;
  const int ks = w >> 1;
  const int r0 = rowg * 8;
  const int c0 = lane * 4;

  // s-phase mapping: zg = lane, srowg = rowg, sks = tid>>7
  const int sks = tid >> 7;
  const int zg = lane;

  // loop-invariant params (used by finalize threads; cheap for all)
  const float4 bb4  = *reinterpret_cast<const float4*>(&bbv_[c0]);
  const float4 wa04 = *reinterpret_cast<const float4*>(&Wa[c0]);
  const float4 wa14 = *reinterpret_cast<const float4*>(&Wa[kH + c0]);
  const float4 wa24 = *reinterpret_cast<const float4*>(&Wa[2 * kH + c0]);
  const float4 wrb4 = *reinterpret_cast<const float4*>(&wrb[c0]);
  const float bsv = bs_[zg], wrsv = wrs[zg];

  // stage belief: sBc[k][r] replicated across 16 rows
  if (tid < kH) {
    float v = belief[batch * kH + tid];
    float4 v4 = make_float4(v, v, v, v);
    float* p = &sBc[tid * kRowsB];
    *reinterpret_cast<float4*>(p + 0) = v4;
    *reinterpret_cast<float4*>(p + 4) = v4;
    *reinterpret_cast<float4*>(p + 8) = v4;
    *reinterpret_cast<float4*>(p + 12) = v4;
  }
  // stage all 12 steps of actions
  for (int i = tid; i < kPH * kRowsB; i += 512) {
    int ph = i >> 4, r = i & 15;
    int gr = row0 + r;
    sAD[ph][r] = discA[ph * kRT + gr];
    sA0[ph][r] = contA[(ph * kRT + gr) * 2 + 0];
    sA1[ph][r] = contA[(ph * kRT + gr) * 2 + 1];
  }

  float rsum[8] = {0,0,0,0,0,0,0,0};
  float ssum[8] = {0,0,0,0,0,0,0,0};
  __syncthreads();

  const float* bKb = sBc + (ks * 64) * kRowsB + r0;       // b-loop LDS base
  const float* wB  = Wb + (size_t)(ks * 64) * kH + c0;    // Wb base (L2)
  const float* bKs = sBc + (sks * 64) * kRowsB + r0;      // s-loop LDS base
  const float* wS  = Ws + (size_t)(sks * 64) * kZ + zg;   // Ws base (L2)

  #pragma unroll 1
  for (int ph = 0; ph < kPH; ++ph) {
    // ---- b' partials: 8 rows x 4 cols over this wave's 64 k ----
    float acc[8][4];
    #pragma unroll
    for (int i = 0; i < 8; ++i)
      #pragma unroll
      for (int j = 0; j < 4; ++j) acc[i][j] = 0.0f;

    #pragma unroll 4
    for (int k = 0; k < 64; ++k) {
      float4 b0 = *reinterpret_cast<const float4*>(bKb + k * kRowsB);
      float4 b1 = *reinterpret_cast<const float4*>(bKb + k * kRowsB + 4);
      float4 wv = *reinterpret_cast<const float4*>(wB + (size_t)k * kH);
      float bvr[8] = {b0.x, b0.y, b0.z, b0.w, b1.x, b1.y, b1.z, b1.w};
      #pragma unroll
      for (int i = 0; i < 8; ++i) {
        acc[i][0] = fmaf(bvr[i], wv.x, acc[i][0]);
        acc[i][1] = fmaf(bvr[i], wv.y, acc[i][1]);
        acc[i][2] = fmaf(bvr[i], wv.z, acc[i][2]);
        acc[i][3] = fmaf(bvr[i], wv.w, acc[i][3]);
      }
    }
    if (ks != 0) {
      #pragma unroll
      for (int i = 0; i < 8; ++i)
        *reinterpret_cast<float4*>(&pT[ks - 1][r0 + i][c0]) =
            make_float4(acc[i][0], acc[i][1], acc[i][2], acc[i][3]);
    }
    __syncthreads();                          // (1) pT ready

    if (ks == 0) {
      #pragma unroll
      for (int i = 0; i < 8; ++i) {
        int r = r0 + i;
        float4 p0 = *reinterpret_cast<const float4*>(&pT[0][r][c0]);
        float4 p1 = *reinterpret_cast<const float4*>(&pT[1][r][c0]);
        float4 p2 = *reinterpret_cast<const float4*>(&pT[2][r][c0]);
        float aD = sAD[ph][r], a0 = sA0[ph][r], a1 = sA1[ph][r];
        float t0 = ((acc[i][0] + p0.x) + p1.x) + p2.x + bb4.x
                   + aD * wa04.x + a0 * wa14.x + a1 * wa24.x;
        float t1 = ((acc[i][1] + p0.y) + p1.y) + p2.y + bb4.y
                   + aD * wa04.y + a0 * wa14.y + a1 * wa24.y;
        float t2 = ((acc[i][2] + p0.z) + p1.z) + p2.z + bb4.z
                   + aD * wa04.z + a0 * wa14.z + a1 * wa24.z;
        float t3 = ((acc[i][3] + p0.w) + p1.w) + p2.w + bb4.w
                   + aD * wa04.w + a0 * wa14.w + a1 * wa24.w;
        float n0 = tanhf(t0), n1 = tanhf(t1), n2 = tanhf(t2), n3 = tanhf(t3);
        acc[i][0] = n0; acc[i][1] = n1; acc[i][2] = n2; acc[i][3] = n3;
        rsum[i] = fmaf(n0, wrb4.x, rsum[i]);
        rsum[i] = fmaf(n1, wrb4.y, rsum[i]);
        rsum[i] = fmaf(n2, wrb4.z, rsum[i]);
        rsum[i] = fmaf(n3, wrb4.w, rsum[i]);
      }
      // write b' back: col-major sBc[c][r], 2 x b128 per col
      #pragma unroll
      for (int j = 0; j < 4; ++j) {
        float* p = &sBc[(c0 + j) * kRowsB + r0];
        *reinterpret_cast<float4*>(p) =
            make_float4(acc[0][j], acc[1][j], acc[2][j], acc[3][j]);
        *reinterpret_cast<float4*>(p + 4) =
            make_float4(acc[4][j], acc[5][j], acc[6][j], acc[7][j]);
      }
    }
    __syncthreads();                          // (2) new belief visible

    // ---- s partials: 8 rows x 1 z over this wave's 64 k ----
    float sa[8] = {0,0,0,0,0,0,0,0};
    #pragma unroll 4
    for (int k = 0; k < 64; ++k) {
      float4 b0 = *reinterpret_cast<const float4*>(bKs + k * kRowsB);
      float4 b1 = *reinterpret_cast<const float4*>(bKs + k * kRowsB + 4);
      float wv = wS[(size_t)k * kZ];
      sa[0] = fmaf(b0.x, wv, sa[0]);
      sa[1] = fmaf(b0.y, wv, sa[1]);
      sa[2] = fmaf(b0.z, wv, sa[2]);
      sa[3] = fmaf(b0.w, wv, sa[3]);
      sa[4] = fmaf(b1.x, wv, sa[4]);
      sa[5] = fmaf(b1.y, wv, sa[5]);
      sa[6] = fmaf(b1.z, wv, sa[6]);
      sa[7] = fmaf(b1.w, wv, sa[7]);
    }
    if (sks != 0) {
      #pragma unroll
      for (int i = 0; i < 8; ++i) sPT[sks - 1][r0 + i][zg] = sa[i];
    }
    __syncthreads();                          // (3) s-partials ready

    if (sks == 0) {
      #pragma unroll
      for (int i = 0; i < 8; ++i) {
        int r = r0 + i;
        float t = ((sa[i] + sPT[0][r][zg]) + sPT[1][r][zg]) + sPT[2][r][zg] + bsv;
        float sv = tanhf(t);
        ssum[i] = fmaf(sv, wrsv, ssum[i]);
      }
    }
    // next step's pT writes are separated from this step's pT reads by
    // barriers (2)+(3); sPT reads (here) precede next sPT writes by
    // next (1)+(2). sBc reads/writes likewise separated. 3 barriers/step.
  }

  // final: rsum+ssum live in waves 0,1 (tid<128), same rows for both.
  if (tid < 128) {
    #pragma unroll
    for (int i = 0; i < 8; ++i) {
      float v = rsum[i] + ssum[i];
      v += __shfl_xor(v, 1, 64);
      v += __shfl_xor(v, 2, 64);
      v += __shfl_xor(v, 4, 64);
      v += __shfl_xor(v, 8, 64);
      v += __shfl_xor(v, 16, 64);
      v += __shfl_xor(v, 32, 64);
      if (lane == 0) ret[row0 + r0 + i] = v;
    }
  }
}

// ---------------- per-batch top-k + statistics -----------------------------
__global__ __launch_bounds__(256) void k_topk_stats(
    const float* __restrict__ ret, const float* __restrict__ discA,
    const float* __restrict__ contA, float* __restrict__ freq,
    float* __restrict__ lfreq, float* __restrict__ meanv,
    float* __restrict__ stdv) {
  __shared__ float rv[kCand];
  __shared__ int selc[kTopK];
  __shared__ int hist[kTools];
  const int b = blockIdx.x, tid = threadIdx.x;
  for (int i = tid; i < kCand; i += 256) rv[i] = ret[b * kCand + i];
  __syncthreads();
  for (int c = tid; c < kCand; c += 256) {
    float v = rv[c];
    int rank = 0;
    for (int o = 0; o < kCand; ++o) {
      float vo = rv[o];
      rank += ((vo > v) || (vo == v && o < c)) ? 1 : 0;
    }
    if (rank < kTopK) selc[rank] = c;
  }
  __syncthreads();
  for (int ph = 0; ph < kPH; ++ph) {
    if (tid < kTools) hist[tid] = 0;
    __syncthreads();
    if (tid < kTopK) {
      int c = selc[tid];
      int idx = ph * kRT + b * kCand + c;
      int d = (int)discA[idx];
      atomicAdd(&hist[d], 1);
      float c0 = contA[idx * 2 + 0];
      float c1 = contA[idx * 2 + 1];
      float s0 = c0, s1 = c1;
      #pragma unroll
      for (int sh = 1; sh < 64; sh <<= 1) {
        s0 += __shfl_xor(s0, sh, 64);
        s1 += __shfl_xor(s1, sh, 64);
      }
      float m0 = s0 * (1.0f / 64.0f);
      float m1 = s1 * (1.0f / 64.0f);
      float d0 = c0 - m0, d1 = c1 - m1;
      float q0 = d0 * d0, q1 = d1 * d1;
      #pragma unroll
      for (int sh = 1; sh < 64; sh <<= 1) {
        q0 += __shfl_xor(q0, sh, 64);
        q1 += __shfl_xor(q1, sh, 64);
      }
      if (tid == 0) {
        int o = (ph * kB + b) * 2;
        meanv[o + 0] = m0;
        meanv[o + 1] = m1;
        stdv[o + 0] = sqrtf(q0 * (1.0f / 64.0f));
        stdv[o + 1] = sqrtf(q1 * (1.0f / 64.0f));
      }
    }
    __syncthreads();
    if (tid < kTools) {
      float fq = (float)(hist[tid] + 1) / 100.0f;
      int o = (ph * kB + b) * kTools + tid;
      freq[o] = fq;
      lfreq[o] = (float)log((double)fq);
    }
    __syncthreads();
  }
}

// ---------------- final output ---------------------------------------------
__global__ void k_final(const float* __restrict__ freq,
                        const float* __restrict__ meanv,
                        float* __restrict__ out) {
  int b = threadIdx.x;
  if (b < kB) {
    const float* f = freq + b * kTools;   // ph = 0
    int best = 0; float bv = f[0];
    for (int t = 1; t < kTools; ++t)
      if (f[t] > bv) { bv = f[t]; best = t; }
    out[b * 3 + 0] = (float)best;
    out[b * 3 + 1] = meanv[b * 2 + 0];
    out[b * 3 + 2] = meanv[b * 2 + 1];
  }
}

extern "C" void kernel_launch(void* const* d_in, const int* in_sizes, int n_in,
                              void* d_out, int out_size, void* d_ws, size_t ws_size,
                              hipStream_t stream) {
  (void)in_sizes; (void)n_in; (void)out_size; (void)ws_size;
  const float* belief = (const float*)d_in[0];
  const float* Wb  = (const float*)d_in[2];
  const float* Wa  = (const float*)d_in[3];
  const float* bb  = (const float*)d_in[4];
  const float* Ws  = (const float*)d_in[5];
  const float* bs  = (const float*)d_in[6];
  const float* wrb = (const float*)d_in[7];
  const float* wrs = (const float*)d_in[8];
  float* out = (float*)d_out;

  float* w = (float*)d_ws;
  float* discA = w;                          // PH*RT
  float* contA = discA + kPH * kRT;          // PH*RT*2
  float* ret   = contA + kPH * kRT * 2;      // RT
  float* freq  = ret + kRT;                  // PH*B*NTOOLS
  float* lfreq = freq + kPH * kB * kTools;   // PH*B*NTOOLS
  float* meanv = lfreq + kPH * kB * kTools;  // PH*B*2
  float* stdv  = meanv + kPH * kB * 2;       // PH*B*2

  uint32_t key0 = 0u, key1 = 42u;            // jax.random.key(42)
  for (int it = 0; it < 3; ++it) {
    uint32_t ks[3][2];
    host_split3(key0, key1, ks);
    int it0 = (it == 0) ? 1 : 0;
    k_sample_disc<<<dim3((kCand * kPH * kB + 255) / 256), dim3(256), 0, stream>>>(
        ks[0][0], ks[0][1], lfreq, discA, it0);
    k_sample_cont<<<dim3((kContTotal + 255) / 256), dim3(256), 0, stream>>>(
        ks[1][0], ks[1][1], meanv, stdv, contA, it0);
    k_rollout<<<dim3(kRT / kRowsB), dim3(512), 0, stream>>>(
        belief, discA, contA, Wb, Wa, bb, Ws, bs, wrb, wrs, ret);
    k_topk_stats<<<dim3(kB), dim3(256), 0, stream>>>(
        ret, discA, contA, freq, lfreq, meanv, stdv);
    key0 = ks[2][0]; key1 = ks[2][1];
  }
  k_final<<<dim3(1), dim3(64), 0, stream>>>(freq, meanv, out);
}

// Round 9
// 1110.384 us; speedup vs baseline: 1.9983x; 1.0107x over previous
//
#include <hip/hip_runtime.h>
#include <cstdint>
#include <cmath>

#define PARTITIONABLE 1

constexpr int kPH = 12;
constexpr int kB = 16;
constexpr int kH = 256;
constexpr int kZ = 64;
constexpr int kCand = 512;
constexpr int kTopK = 64;
constexpr int kTools = 36;
constexpr int kRT = kB * kCand;   // 8192 rows
constexpr uint32_t kDiscTotal = (uint32_t)kCand * kPH * kB * kTools; // 3538944
constexpr uint32_t kContTotal = (uint32_t)kPH * kB * kCand * 2;      // 196608

constexpr int kRowsB = 8;         // rows per rollout block
constexpr int kSB = 12;           // sBc column stride (words); 48B, b128-aligned

// ---------------- Threefry-2x32 (JAX-exact: 20 rounds, 5 key injections) ---
__host__ __device__ inline void tf2x32(uint32_t k0, uint32_t k1,
                                       uint32_t x0, uint32_t x1,
                                       uint32_t& o0, uint32_t& o1) {
  uint32_t ks2 = k0 ^ k1 ^ 0x1BD11BDAu;
  x0 += k0; x1 += k1;
#define TFROT(v, d) (((v) << (d)) | ((v) >> (32 - (d))))
#define TFR(r) { x0 += x1; x1 = TFROT(x1, r); x1 ^= x0; }
  TFR(13) TFR(15) TFR(26) TFR(6)
  x0 += k1;  x1 += ks2 + 1u;
  TFR(17) TFR(29) TFR(16) TFR(24)
  x0 += ks2; x1 += k0 + 2u;
  TFR(13) TFR(15) TFR(26) TFR(6)
  x0 += k0;  x1 += k1 + 3u;
  TFR(17) TFR(29) TFR(16) TFR(24)
  x0 += k1;  x1 += ks2 + 4u;
  TFR(13) TFR(15) TFR(26) TFR(6)
  x0 += ks2; x1 += k0 + 5u;
#undef TFR
#undef TFROT
  o0 = x0; o1 = x1;
}

__device__ inline uint32_t jax_bits32(uint32_t k0, uint32_t k1,
                                      uint32_t idx, uint32_t total) {
#if PARTITIONABLE
  (void)total;
  uint32_t y0, y1;
  tf2x32(k0, k1, 0u, idx, y0, y1);
  return y0 ^ y1;
#else
  uint32_t half = total >> 1;
  uint32_t y0, y1;
  if (idx < half) { tf2x32(k0, k1, idx, idx + half, y0, y1); return y0; }
  else            { tf2x32(k0, k1, idx - half, idx, y0, y1); return y1; }
#endif
}

static void host_split3(uint32_t k0, uint32_t k1, uint32_t out[3][2]) {
#if PARTITIONABLE
  for (uint32_t i = 0; i < 3; ++i)
    tf2x32(k0, k1, 0u, i, out[i][0], out[i][1]);
#else
  uint32_t a0,a1,b0,b1,c0,c1;
  tf2x32(k0, k1, 0u, 3u, a0, a1);
  tf2x32(k0, k1, 1u, 4u, b0, b1);
  tf2x32(k0, k1, 2u, 5u, c0, c1);
  out[0][0]=a0; out[0][1]=b0;
  out[1][0]=c0; out[1][1]=a1;
  out[2][0]=b1; out[2][1]=c1;
#endif
}

// ---------------- XLA f32 erf_inv (Giles polynomial) -----------------------
__device__ inline float erfinv_xla(float x) {
  float xx = x * x;
  float w = -(float)log1p((double)(-xx));
  float p;
  if (w < 5.0f) {
    float ww = w - 2.5f;
    p = 2.81022636e-08f;
    p = fmaf(p, ww, 3.43273939e-07f);
    p = fmaf(p, ww, -3.5233877e-06f);
    p = fmaf(p, ww, -4.39150654e-06f);
    p = fmaf(p, ww, 0.00021858087f);
    p = fmaf(p, ww, -0.00125372503f);
    p = fmaf(p, ww, -0.00417768164f);
    p = fmaf(p, ww, 0.246640727f);
    p = fmaf(p, ww, 1.50140941f);
  } else {
    float ww = sqrtf(w) - 3.0f;
    p = -0.000200214257f;
    p = fmaf(p, ww, 0.000100950558f);
    p = fmaf(p, ww, 0.00134934322f);
    p = fmaf(p, ww, -0.00367342844f);
    p = fmaf(p, ww, 0.00573950773f);
    p = fmaf(p, ww, -0.0076224613f);
    p = fmaf(p, ww, 0.00943887047f);
    p = fmaf(p, ww, 1.00167406f);
    p = fmaf(p, ww, 2.83297682f);
  }
  return p * x;
}

// ---------------- categorical sampling (disc actions) ----------------------
__global__ __launch_bounds__(256) void k_sample_disc(
    uint32_t kd0, uint32_t kd1, const float* __restrict__ lfreq,
    float* __restrict__ discA, int it0) {
  int gid = blockIdx.x * 256 + threadIdx.x;   // gid = c*(PH*B) + j
  if (gid >= kCand * kPH * kB) return;
  int c = gid / (kPH * kB);
  int j = gid - c * (kPH * kB);               // j = ph*16 + b
  int best = 0;
  if (it0) {
    uint32_t bm = 0u;
    for (int t = 0; t < kTools; ++t) {
      uint32_t bits = jax_bits32(kd0, kd1, (uint32_t)(gid * kTools + t), kDiscTotal);
      uint32_t m = bits >> 9;
      if (t == 0 || m > bm) { bm = m; best = t; }
    }
  } else {
    const float* lf = lfreq + j * kTools;
    float bv = 0.0f;
    for (int t = 0; t < kTools; ++t) {
      uint32_t bits = jax_bits32(kd0, kd1, (uint32_t)(gid * kTools + t), kDiscTotal);
      float u = __uint_as_float((bits >> 9) | 0x3F800000u) - 1.0f;
      if (u == 0.0f) u = 1.17549435e-38f;
      float l1 = (float)log((double)u);
      float g = -(float)log((double)(-l1));
      float val = g + lf[t];
      if (t == 0 || val > bv) { bv = val; best = t; }
    }
  }
  int ph = j >> 4, b = j & 15;
  discA[ph * kRT + b * kCand + c] = (float)best;
}

// ---------------- normal sampling (cont actions) ---------------------------
__global__ __launch_bounds__(256) void k_sample_cont(
    uint32_t kn0, uint32_t kn1, const float* __restrict__ meanv,
    const float* __restrict__ stdv, float* __restrict__ contA, int it0) {
  int gid = blockIdx.x * 256 + threadIdx.x;
  if (gid >= (int)kContTotal) return;
  uint32_t bits = jax_bits32(kn0, kn1, (uint32_t)gid, kContTotal);
  float f = __uint_as_float((bits >> 9) | 0x3F800000u) - 1.0f;
  const float lo = -0.99999994f;
  float u = fmaxf(lo, f * 2.0f + lo);
  float n = __uint_as_float(0x3FB504F3u) * erfinv_xla(u);
  int d = gid & 1;
  int c = (gid >> 1) & (kCand - 1);
  int rest = gid >> 10;                        // ph*16 + b
  int ph = rest >> 4, b = rest & 15;
  float m, s;
  if (it0) { m = 0.0f; s = 1.0f; }
  else {
    m = meanv[rest * 2 + d];
    s = stdv[rest * 2 + d];
  }
  float x = m + s * n;
  x = fminf(fmaxf(x, -1.0f), 1.0f);
  contA[(ph * kRT + b * kCand + c) * 2 + d] = x;
}

// ---------------- fused 12-step rollout ------------------------------------
// 1024 blocks x 8 rows x 256 threads (4 waves; 4 blocks/CU = 16 waves/CU).
// b-phase: wave w = k-quarter; 64 lanes span all 64 col-groups -> Wb float4
// loads fully coalesced (1 VMEM per 32 FMA). Partials through 2 LDS planes:
// w2->A, w3->B; then w1 RMW A, w0 RMW B; then ALL waves finalize 2 rows each
// (no idle-wave serialization). s-phase mirrors with scalar Ws loads.
// 5 barriers/step on 4-wave groups; 4 independent blocks/CU hide the stalls.
__global__ __launch_bounds__(256) void k_rollout(
    const float* __restrict__ belief,
    const float* __restrict__ discA, const float* __restrict__ contA,
    const float* __restrict__ Wb, const float* __restrict__ Wa,
    const float* __restrict__ bbv_, const float* __restrict__ Ws,
    const float* __restrict__ bs_, const float* __restrict__ wrb,
    const float* __restrict__ wrs, float* __restrict__ ret) {
  __shared__ float sBc[kH * kSB];             // 12 KB, [c][r] stride 12
  __shared__ float pA[kRowsB][kH];            // 8 KB  b-partials (w2 + w1)
  __shared__ float pB[kRowsB][kH];            // 8 KB  b-partials (w3 + w0)
  __shared__ float sA_[kRowsB][kZ];           // 2 KB  s-partials (w2 + w1)
  __shared__ float sB_[kRowsB][kZ];           // 2 KB  s-partials (w3 + w0)
  __shared__ float sAD[kPH][kRowsB];
  __shared__ float sA0[kPH][kRowsB];
  __shared__ float sA1[kPH][kRowsB];

  const int tid = threadIdx.x;
  const int row0 = blockIdx.x * kRowsB;
  const int batch = row0 >> 9;

  const int w = tid >> 6;            // wave = k-quarter (b) / k-quarter (s)
  const int lane = tid & 63;
  const int c0 = lane * 4;           // owned belief cols c0..c0+3
  const int fr0 = w * 2;             // finalize rows fr0, fr0+1

  // loop-invariant params
  const float4 bb4  = *reinterpret_cast<const float4*>(&bbv_[c0]);
  const float4 wa04 = *reinterpret_cast<const float4*>(&Wa[c0]);
  const float4 wa14 = *reinterpret_cast<const float4*>(&Wa[kH + c0]);
  const float4 wa24 = *reinterpret_cast<const float4*>(&Wa[2 * kH + c0]);
  const float4 wrb4 = *reinterpret_cast<const float4*>(&wrb[c0]);
  const float bsv = bs_[lane], wrsv = wrs[lane];

  // stage belief: sBc[c][r] replicated across 8 rows
  {
    float v = belief[batch * kH + tid];
    float4 v4 = make_float4(v, v, v, v);
    float* p = &sBc[tid * kSB];
    *reinterpret_cast<float4*>(p + 0) = v4;
    *reinterpret_cast<float4*>(p + 4) = v4;
  }
  // stage all 12 steps of actions (96 values)
  if (tid < kPH * kRowsB) {
    int ph = tid >> 3, r = tid & 7;
    int gr = row0 + r;
    sAD[ph][r] = discA[ph * kRT + gr];
    sA0[ph][r] = contA[(ph * kRT + gr) * 2 + 0];
    sA1[ph][r] = contA[(ph * kRT + gr) * 2 + 1];
  }

  float rsum[2] = {0.0f, 0.0f};
  float ssum[2] = {0.0f, 0.0f};
  __syncthreads();

  const float* bKb = sBc + (w * 64) * kSB;                // b-loop LDS base
  const float* wB  = Wb + (size_t)(w * 64) * kH + c0;     // Wb base (L2)
  const float* wS  = Ws + (size_t)(w * 64) * kZ + lane;   // Ws base (L2)

  #pragma unroll 1
  for (int ph = 0; ph < kPH; ++ph) {
    // ---- b' partials: 8 rows x 4 cols over this wave's 64 k ----
    float acc[8][4];
    #pragma unroll
    for (int i = 0; i < 8; ++i)
      #pragma unroll
      for (int j = 0; j < 4; ++j) acc[i][j] = 0.0f;

    #pragma unroll 4
    for (int k = 0; k < 64; ++k) {
      float4 b0 = *reinterpret_cast<const float4*>(bKb + k * kSB);
      float4 b1 = *reinterpret_cast<const float4*>(bKb + k * kSB + 4);
      float4 wv = *reinterpret_cast<const float4*>(wB + (size_t)k * kH);
      float bvr[8] = {b0.x, b0.y, b0.z, b0.w, b1.x, b1.y, b1.z, b1.w};
      #pragma unroll
      for (int i = 0; i < 8; ++i) {
        acc[i][0] = fmaf(bvr[i], wv.x, acc[i][0]);
        acc[i][1] = fmaf(bvr[i], wv.y, acc[i][1]);
        acc[i][2] = fmaf(bvr[i], wv.z, acc[i][2]);
        acc[i][3] = fmaf(bvr[i], wv.w, acc[i][3]);
      }
    }
    // stage 1: w2 -> A, w3 -> B
    if (w == 2) {
      #pragma unroll
      for (int i = 0; i < 8; ++i)
        *reinterpret_cast<float4*>(&pA[i][c0]) =
            make_float4(acc[i][0], acc[i][1], acc[i][2], acc[i][3]);
    } else if (w == 3) {
      #pragma unroll
      for (int i = 0; i < 8; ++i)
        *reinterpret_cast<float4*>(&pB[i][c0]) =
            make_float4(acc[i][0], acc[i][1], acc[i][2], acc[i][3]);
    }
    __syncthreads();                          // (1a) A,B written
    // stage 2: w1 RMW A, w0 RMW B
    if (w == 1) {
      #pragma unroll
      for (int i = 0; i < 8; ++i) {
        float4 t = *reinterpret_cast<const float4*>(&pA[i][c0]);
        *reinterpret_cast<float4*>(&pA[i][c0]) =
            make_float4(t.x + acc[i][0], t.y + acc[i][1],
                        t.z + acc[i][2], t.w + acc[i][3]);
      }
    } else if (w == 0) {
      #pragma unroll
      for (int i = 0; i < 8; ++i) {
        float4 t = *reinterpret_cast<const float4*>(&pB[i][c0]);
        *reinterpret_cast<float4*>(&pB[i][c0]) =
            make_float4(t.x + acc[i][0], t.y + acc[i][1],
                        t.z + acc[i][2], t.w + acc[i][3]);
      }
    }
    __syncthreads();                          // (1b) partials complete
    // stage 3: all waves finalize rows fr0, fr0+1
    float bn[2][4];
    #pragma unroll
    for (int rr = 0; rr < 2; ++rr) {
      int r = fr0 + rr;
      float4 a = *reinterpret_cast<const float4*>(&pA[r][c0]);
      float4 b = *reinterpret_cast<const float4*>(&pB[r][c0]);
      float aD = sAD[ph][r], a0 = sA0[ph][r], a1 = sA1[ph][r];
      float t0 = (a.x + b.x) + bb4.x + aD * wa04.x + a0 * wa14.x + a1 * wa24.x;
      float t1 = (a.y + b.y) + bb4.y + aD * wa04.y + a0 * wa14.y + a1 * wa24.y;
      float t2 = (a.z + b.z) + bb4.z + aD * wa04.z + a0 * wa14.z + a1 * wa24.z;
      float t3 = (a.w + b.w) + bb4.w + aD * wa04.w + a0 * wa14.w + a1 * wa24.w;
      bn[rr][0] = tanhf(t0);
      bn[rr][1] = tanhf(t1);
      bn[rr][2] = tanhf(t2);
      bn[rr][3] = tanhf(t3);
      rsum[rr] = fmaf(bn[rr][0], wrb4.x, rsum[rr]);
      rsum[rr] = fmaf(bn[rr][1], wrb4.y, rsum[rr]);
      rsum[rr] = fmaf(bn[rr][2], wrb4.z, rsum[rr]);
      rsum[rr] = fmaf(bn[rr][3], wrb4.w, rsum[rr]);
    }
    // write b' back: float2 (rows fr0, fr0+1) per col
    #pragma unroll
    for (int j = 0; j < 4; ++j)
      *reinterpret_cast<float2*>(&sBc[(c0 + j) * kSB + fr0]) =
          make_float2(bn[0][j], bn[1][j]);
    __syncthreads();                          // (2) new belief visible

    // ---- s partials: 8 rows x 1 z over this wave's 64 k ----
    float sa[8] = {0,0,0,0,0,0,0,0};
    #pragma unroll 4
    for (int k = 0; k < 64; ++k) {
      float4 b0 = *reinterpret_cast<const float4*>(bKb + k * kSB);
      float4 b1 = *reinterpret_cast<const float4*>(bKb + k * kSB + 4);
      float wv = wS[(size_t)k * kZ];
      sa[0] = fmaf(b0.x, wv, sa[0]);
      sa[1] = fmaf(b0.y, wv, sa[1]);
      sa[2] = fmaf(b0.z, wv, sa[2]);
      sa[3] = fmaf(b0.w, wv, sa[3]);
      sa[4] = fmaf(b1.x, wv, sa[4]);
      sa[5] = fmaf(b1.y, wv, sa[5]);
      sa[6] = fmaf(b1.z, wv, sa[6]);
      sa[7] = fmaf(b1.w, wv, sa[7]);
    }
    if (w == 2) {
      #pragma unroll
      for (int i = 0; i < 8; ++i) sA_[i][lane] = sa[i];
    } else if (w == 3) {
      #pragma unroll
      for (int i = 0; i < 8; ++i) sB_[i][lane] = sa[i];
    }
    __syncthreads();                          // (3a) SA,SB written
    if (w == 1) {
      #pragma unroll
      for (int i = 0; i < 8; ++i) sA_[i][lane] += sa[i];
    } else if (w == 0) {
      #pragma unroll
      for (int i = 0; i < 8; ++i) sB_[i][lane] += sa[i];
    }
    __syncthreads();                          // (3b) s-partials complete
    #pragma unroll
    for (int rr = 0; rr < 2; ++rr) {
      int r = fr0 + rr;
      float t = (sA_[r][lane] + sB_[r][lane]) + bsv;
      float sv = tanhf(t);
      ssum[rr] = fmaf(sv, wrsv, ssum[rr]);
    }
    // next step's A/B writes are >= 2 barriers after this step's reads.
  }

  // final: wave w owns rows fr0, fr0+1; reduce over 64 lanes, lane 0 writes.
  #pragma unroll
  for (int rr = 0; rr < 2; ++rr) {
    float v = rsum[rr] + ssum[rr];
    v += __shfl_xor(v, 1, 64);
    v += __shfl_xor(v, 2, 64);
    v += __shfl_xor(v, 4, 64);
    v += __shfl_xor(v, 8, 64);
    v += __shfl_xor(v, 16, 64);
    v += __shfl_xor(v, 32, 64);
    if (lane == 0) ret[row0 + fr0 + rr] = v;
  }
}

// ---------------- per-batch top-k + statistics -----------------------------
__global__ __launch_bounds__(256) void k_topk_stats(
    const float* __restrict__ ret, const float* __restrict__ discA,
    const float* __restrict__ contA, float* __restrict__ freq,
    float* __restrict__ lfreq, float* __restrict__ meanv,
    float* __restrict__ stdv) {
  __shared__ float rv[kCand];
  __shared__ int selc[kTopK];
  __shared__ int hist[kTools];
  const int b = blockIdx.x, tid = threadIdx.x;
  for (int i = tid; i < kCand; i += 256) rv[i] = ret[b * kCand + i];
  __syncthreads();
  for (int c = tid; c < kCand; c += 256) {
    float v = rv[c];
    int rank = 0;
    for (int o = 0; o < kCand; ++o) {
      float vo = rv[o];
      rank += ((vo > v) || (vo == v && o < c)) ? 1 : 0;
    }
    if (rank < kTopK) selc[rank] = c;
  }
  __syncthreads();
  for (int ph = 0; ph < kPH; ++ph) {
    if (tid < kTools) hist[tid] = 0;
    __syncthreads();
    if (tid < kTopK) {
      int c = selc[tid];
      int idx = ph * kRT + b * kCand + c;
      int d = (int)discA[idx];
      atomicAdd(&hist[d], 1);
      float c0 = contA[idx * 2 + 0];
      float c1 = contA[idx * 2 + 1];
      float s0 = c0, s1 = c1;
      #pragma unroll
      for (int sh = 1; sh < 64; sh <<= 1) {
        s0 += __shfl_xor(s0, sh, 64);
        s1 += __shfl_xor(s1, sh, 64);
      }
      float m0 = s0 * (1.0f / 64.0f);
      float m1 = s1 * (1.0f / 64.0f);
      float d0 = c0 - m0, d1 = c1 - m1;
      float q0 = d0 * d0, q1 = d1 * d1;
      #pragma unroll
      for (int sh = 1; sh < 64; sh <<= 1) {
        q0 += __shfl_xor(q0, sh, 64);
        q1 += __shfl_xor(q1, sh, 64);
      }
      if (tid == 0) {
        int o = (ph * kB + b) * 2;
        meanv[o + 0] = m0;
        meanv[o + 1] = m1;
        stdv[o + 0] = sqrtf(q0 * (1.0f / 64.0f));
        stdv[o + 1] = sqrtf(q1 * (1.0f / 64.0f));
      }
    }
    __syncthreads();
    if (tid < kTools) {
      float fq = (float)(hist[tid] + 1) / 100.0f;
      int o = (ph * kB + b) * kTools + tid;
      freq[o] = fq;
      lfreq[o] = (float)log((double)fq);
    }
    __syncthreads();
  }
}

// ---------------- final output ---------------------------------------------
__global__ void k_final(const float* __restrict__ freq,
                        const float* __restrict__ meanv,
                        float* __restrict__ out) {
  int b = threadIdx.x;
  if (b < kB) {
    const float* f = freq + b * kTools;   // ph = 0
    int best = 0; float bv = f[0];
    for (int t = 1; t < kTools; ++t)
      if (f[t] > bv) { bv = f[t]; best = t; }
    out[b * 3 + 0] = (float)best;
    out[b * 3 + 1] = meanv[b * 2 + 0];
    out[b * 3 + 2] = meanv[b * 2 + 1];
  }
}

extern "C" void kernel_launch(void* const* d_in, const int* in_sizes, int n_in,
                              void* d_out, int out_size, void* d_ws, size_t ws_size,
                              hipStream_t stream) {
  (void)in_sizes; (void)n_in; (void)out_size; (void)ws_size;
  const float* belief = (const float*)d_in[0];
  const float* Wb  = (const float*)d_in[2];
  const float* Wa  = (const float*)d_in[3];
  const float* bb  = (const float*)d_in[4];
  const float* Ws  = (const float*)d_in[5];
  const float* bs  = (const float*)d_in[6];
  const float* wrb = (const float*)d_in[7];
  const float* wrs = (const float*)d_in[8];
  float* out = (float*)d_out;

  float* w = (float*)d_ws;
  float* discA = w;                          // PH*RT
  float* contA = discA + kPH * kRT;          // PH*RT*2
  float* ret   = contA + kPH * kRT * 2;      // RT
  float* freq  = ret + kRT;                  // PH*B*NTOOLS
  float* lfreq = freq + kPH * kB * kTools;   // PH*B*NTOOLS
  float* meanv = lfreq + kPH * kB * kTools;  // PH*B*2
  float* stdv  = meanv + kPH * kB * 2;       // PH*B*2

  uint32_t key0 = 0u, key1 = 42u;            // jax.random.key(42)
  for (int it = 0; it < 3; ++it) {
    uint32_t ks[3][2];
    host_split3(key0, key1, ks);
    int it0 = (it == 0) ? 1 : 0;
    k_sample_disc<<<dim3((kCand * kPH * kB + 255) / 256), dim3(256), 0, stream>>>(
        ks[0][0], ks[0][1], lfreq, discA, it0);
    k_sample_cont<<<dim3((kContTotal + 255) / 256), dim3(256), 0, stream>>>(
        ks[1][0], ks[1][1], meanv, stdv, contA, it0);
    k_rollout<<<dim3(kRT / kRowsB), dim3(256), 0, stream>>>(
        belief, discA, contA, Wb, Wa, bb, Ws, bs, wrb, wrs, ret);
    k_topk_stats<<<dim3(kB), dim3(256), 0, stream>>>(
        ret, discA, contA, freq, lfreq, meanv, stdv);
    key0 = ks[2][0]; key1 = ks[2][1];
  }
  k_final<<<dim3(1), dim3(64), 0, stream>>>(freq, meanv, out);
}

// Round 11
// 1083.244 us; speedup vs baseline: 2.0484x; 1.0251x over previous
//
#include <hip/hip_runtime.h>
#include <cstdint>
#include <cmath>

#define PARTITIONABLE 1

constexpr int kPH = 12;
constexpr int kB = 16;
constexpr int kH = 256;
constexpr int kZ = 64;
constexpr int kCand = 512;
constexpr int kTopK = 64;
constexpr int kTools = 36;
constexpr int kRT = kB * kCand;   // 8192 rows
constexpr uint32_t kDiscTotal = (uint32_t)kCand * kPH * kB * kTools; // 3538944
constexpr uint32_t kContTotal = (uint32_t)kPH * kB * kCand * 2;      // 196608

constexpr int kRowsB = 8;         // rows per rollout block
constexpr int kSB = 12;           // sBc column stride (words); 48B, b128-aligned

// ---------------- Threefry-2x32 (JAX-exact: 20 rounds, 5 key injections) ---
__host__ __device__ inline void tf2x32(uint32_t k0, uint32_t k1,
                                       uint32_t x0, uint32_t x1,
                                       uint32_t& o0, uint32_t& o1) {
  uint32_t ks2 = k0 ^ k1 ^ 0x1BD11BDAu;
  x0 += k0; x1 += k1;
#define TFROT(v, d) (((v) << (d)) | ((v) >> (32 - (d))))
#define TFR(r) { x0 += x1; x1 = TFROT(x1, r); x1 ^= x0; }
  TFR(13) TFR(15) TFR(26) TFR(6)
  x0 += k1;  x1 += ks2 + 1u;
  TFR(17) TFR(29) TFR(16) TFR(24)
  x0 += ks2; x1 += k0 + 2u;
  TFR(13) TFR(15) TFR(26) TFR(6)
  x0 += k0;  x1 += k1 + 3u;
  TFR(17) TFR(29) TFR(16) TFR(24)
  x0 += k1;  x1 += ks2 + 4u;
  TFR(13) TFR(15) TFR(26) TFR(6)
  x0 += ks2; x1 += k0 + 5u;
#undef TFR
#undef TFROT
  o0 = x0; o1 = x1;
}

__device__ inline uint32_t jax_bits32(uint32_t k0, uint32_t k1,
                                      uint32_t idx, uint32_t total) {
#if PARTITIONABLE
  (void)total;
  uint32_t y0, y1;
  tf2x32(k0, k1, 0u, idx, y0, y1);
  return y0 ^ y1;
#else
  uint32_t half = total >> 1;
  uint32_t y0, y1;
  if (idx < half) { tf2x32(k0, k1, idx, idx + half, y0, y1); return y0; }
  else            { tf2x32(k0, k1, idx - half, idx, y0, y1); return y1; }
#endif
}

static void host_split3(uint32_t k0, uint32_t k1, uint32_t out[3][2]) {
#if PARTITIONABLE
  for (uint32_t i = 0; i < 3; ++i)
    tf2x32(k0, k1, 0u, i, out[i][0], out[i][1]);
#else
  uint32_t a0,a1,b0,b1,c0,c1;
  tf2x32(k0, k1, 0u, 3u, a0, a1);
  tf2x32(k0, k1, 1u, 4u, b0, b1);
  tf2x32(k0, k1, 2u, 5u, c0, c1);
  out[0][0]=a0; out[0][1]=b0;
  out[1][0]=c0; out[1][1]=a1;
  out[2][0]=b1; out[2][1]=c1;
#endif
}

// ---------------- XLA f32 erf_inv (Giles polynomial) -----------------------
__device__ inline float erfinv_xla(float x) {
  float xx = x * x;
  float w = -(float)log1p((double)(-xx));
  float p;
  if (w < 5.0f) {
    float ww = w - 2.5f;
    p = 2.81022636e-08f;
    p = fmaf(p, ww, 3.43273939e-07f);
    p = fmaf(p, ww, -3.5233877e-06f);
    p = fmaf(p, ww, -4.39150654e-06f);
    p = fmaf(p, ww, 0.00021858087f);
    p = fmaf(p, ww, -0.00125372503f);
    p = fmaf(p, ww, -0.00417768164f);
    p = fmaf(p, ww, 0.246640727f);
    p = fmaf(p, ww, 1.50140941f);
  } else {
    float ww = sqrtf(w) - 3.0f;
    p = -0.000200214257f;
    p = fmaf(p, ww, 0.000100950558f);
    p = fmaf(p, ww, 0.00134934322f);
    p = fmaf(p, ww, -0.00367342844f);
    p = fmaf(p, ww, 0.00573950773f);
    p = fmaf(p, ww, -0.0076224613f);
    p = fmaf(p, ww, 0.00943887047f);
    p = fmaf(p, ww, 1.00167406f);
    p = fmaf(p, ww, 2.83297682f);
  }
  return p * x;
}

// ---------------- categorical sampling (disc actions) ----------------------
__global__ __launch_bounds__(256) void k_sample_disc(
    uint32_t kd0, uint32_t kd1, const float* __restrict__ lfreq,
    float* __restrict__ discA, int it0) {
  int gid = blockIdx.x * 256 + threadIdx.x;   // gid = c*(PH*B) + j
  if (gid >= kCand * kPH * kB) return;
  int c = gid / (kPH * kB);
  int j = gid - c * (kPH * kB);               // j = ph*16 + b
  int best = 0;
  if (it0) {
    uint32_t bm = 0u;
    for (int t = 0; t < kTools; ++t) {
      uint32_t bits = jax_bits32(kd0, kd1, (uint32_t)(gid * kTools + t), kDiscTotal);
      uint32_t m = bits >> 9;
      if (t == 0 || m > bm) { bm = m; best = t; }
    }
  } else {
    const float* lf = lfreq + j * kTools;
    float bv = 0.0f;
    for (int t = 0; t < kTools; ++t) {
      uint32_t bits = jax_bits32(kd0, kd1, (uint32_t)(gid * kTools + t), kDiscTotal);
      float u = __uint_as_float((bits >> 9) | 0x3F800000u) - 1.0f;
      if (u == 0.0f) u = 1.17549435e-38f;
      float l1 = (float)log((double)u);
      float g = -(float)log((double)(-l1));
      float val = g + lf[t];
      if (t == 0 || val > bv) { bv = val; best = t; }
    }
  }
  int ph = j >> 4, b = j & 15;
  discA[ph * kRT + b * kCand + c] = (float)best;
}

// ---------------- normal sampling (cont actions) ---------------------------
__global__ __launch_bounds__(256) void k_sample_cont(
    uint32_t kn0, uint32_t kn1, const float* __restrict__ meanv,
    const float* __restrict__ stdv, float* __restrict__ contA, int it0) {
  int gid = blockIdx.x * 256 + threadIdx.x;
  if (gid >= (int)kContTotal) return;
  uint32_t bits = jax_bits32(kn0, kn1, (uint32_t)gid, kContTotal);
  float f = __uint_as_float((bits >> 9) | 0x3F800000u) - 1.0f;
  const float lo = -0.99999994f;
  float u = fmaxf(lo, f * 2.0f + lo);
  float n = __uint_as_float(0x3FB504F3u) * erfinv_xla(u);
  int d = gid & 1;
  int c = (gid >> 1) & (kCand - 1);
  int rest = gid >> 10;                        // ph*16 + b
  int ph = rest >> 4, b = rest & 15;
  float m, s;
  if (it0) { m = 0.0f; s = 1.0f; }
  else {
    m = meanv[rest * 2 + d];
    s = stdv[rest * 2 + d];
  }
  float x = m + s * n;
  x = fminf(fmaxf(x, -1.0f), 1.0f);
  contA[(ph * kRT + b * kCand + c) * 2 + d] = x;
}

// ---------------- fused 12-step rollout ------------------------------------
// 1024 blocks x 8 rows x 256 threads (4 waves; 4 blocks/CU = 16 waves/CU).
// b-phase: wave w = k-quarter; 64 lanes span all 64 col-groups -> Wb float4
// loads fully coalesced (1 VMEM per 32 FMA). Partials via 2 LDS planes.
// s-phase: Ws slice lives in REGISTERS (wsr[64], loaded once) -> zero VMEM
// in the steady state beyond Wb. Finalize params come from an LDS table to
// keep VGPR <= 128 (4 waves/SIMD).
__global__ __launch_bounds__(256, 4) void k_rollout(
    const float* __restrict__ belief,
    const float* __restrict__ discA, const float* __restrict__ contA,
    const float* __restrict__ Wb, const float* __restrict__ Wa,
    const float* __restrict__ bbv_, const float* __restrict__ Ws,
    const float* __restrict__ bs_, const float* __restrict__ wrb,
    const float* __restrict__ wrs, float* __restrict__ ret) {
  __shared__ float sBc[kH * kSB];             // 12 KB, [c][r] stride 12
  __shared__ float pA[kRowsB][kH];            // 8 KB  b-partials (w2 + w1)
  __shared__ float pB[kRowsB][kH];            // 8 KB  b-partials (w3 + w0)
  __shared__ float sA_[kRowsB][kZ];           // 2 KB  s-partials (w2 + w1)
  __shared__ float sB_[kRowsB][kZ];           // 2 KB  s-partials (w3 + w0)
  __shared__ float sPar[5][kH];               // 5 KB  bb, Wa0..2, wrb
  __shared__ float sAD[kPH][kRowsB];
  __shared__ float sA0[kPH][kRowsB];
  __shared__ float sA1[kPH][kRowsB];

  const int tid = threadIdx.x;
  const int row0 = blockIdx.x * kRowsB;
  const int batch = row0 >> 9;

  const int w = tid >> 6;            // wave = k-quarter
  const int lane = tid & 63;
  const int c0 = lane * 4;           // owned belief cols c0..c0+3
  const int fr0 = w * 2;             // finalize rows fr0, fr0+1

  const float bsv = bs_[lane], wrsv = wrs[lane];

  // Ws slice into registers: wsr[k] = Ws[w*64+k][lane]  (coalesced, once)
  float wsr[64];
  #pragma unroll
  for (int k = 0; k < 64; ++k)
    wsr[k] = Ws[(size_t)(w * 64 + k) * kZ + lane];

  // stage belief: sBc[c][r] replicated across 8 rows
  {
    float v = belief[batch * kH + tid];
    float4 v4 = make_float4(v, v, v, v);
    float* p = &sBc[tid * kSB];
    *reinterpret_cast<float4*>(p + 0) = v4;
    *reinterpret_cast<float4*>(p + 4) = v4;
  }
  // finalize-param table
  sPar[0][tid] = bbv_[tid];
  sPar[1][tid] = Wa[tid];
  sPar[2][tid] = Wa[kH + tid];
  sPar[3][tid] = Wa[2 * kH + tid];
  sPar[4][tid] = wrb[tid];
  // stage all 12 steps of actions (96 values)
  if (tid < kPH * kRowsB) {
    int ph = tid >> 3, r = tid & 7;
    int gr = row0 + r;
    sAD[ph][r] = discA[ph * kRT + gr];
    sA0[ph][r] = contA[(ph * kRT + gr) * 2 + 0];
    sA1[ph][r] = contA[(ph * kRT + gr) * 2 + 1];
  }

  float rsum[2] = {0.0f, 0.0f};
  float ssum[2] = {0.0f, 0.0f};
  __syncthreads();

  const float* bKb = sBc + (w * 64) * kSB;                // b-loop LDS base
  const float* wB  = Wb + (size_t)(w * 64) * kH + c0;     // Wb base (L2)

  #pragma unroll 1
  for (int ph = 0; ph < kPH; ++ph) {
    // ---- b' partials: 8 rows x 4 cols over this wave's 64 k ----
    float acc[8][4];
    #pragma unroll
    for (int i = 0; i < 8; ++i)
      #pragma unroll
      for (int j = 0; j < 4; ++j) acc[i][j] = 0.0f;

    #pragma unroll 4
    for (int k = 0; k < 64; ++k) {
      float4 b0 = *reinterpret_cast<const float4*>(bKb + k * kSB);
      float4 b1 = *reinterpret_cast<const float4*>(bKb + k * kSB + 4);
      float4 wv = *reinterpret_cast<const float4*>(wB + (size_t)k * kH);
      float bvr[8] = {b0.x, b0.y, b0.z, b0.w, b1.x, b1.y, b1.z, b1.w};
      #pragma unroll
      for (int i = 0; i < 8; ++i) {
        acc[i][0] = fmaf(bvr[i], wv.x, acc[i][0]);
        acc[i][1] = fmaf(bvr[i], wv.y, acc[i][1]);
        acc[i][2] = fmaf(bvr[i], wv.z, acc[i][2]);
        acc[i][3] = fmaf(bvr[i], wv.w, acc[i][3]);
      }
    }
    // stage 1: w2 -> A, w3 -> B
    if (w == 2) {
      #pragma unroll
      for (int i = 0; i < 8; ++i)
        *reinterpret_cast<float4*>(&pA[i][c0]) =
            make_float4(acc[i][0], acc[i][1], acc[i][2], acc[i][3]);
    } else if (w == 3) {
      #pragma unroll
      for (int i = 0; i < 8; ++i)
        *reinterpret_cast<float4*>(&pB[i][c0]) =
            make_float4(acc[i][0], acc[i][1], acc[i][2], acc[i][3]);
    }
    __syncthreads();                          // (1a) A,B written
    // stage 2: w1 RMW A, w0 RMW B
    if (w == 1) {
      #pragma unroll
      for (int i = 0; i < 8; ++i) {
        float4 t = *reinterpret_cast<const float4*>(&pA[i][c0]);
        *reinterpret_cast<float4*>(&pA[i][c0]) =
            make_float4(t.x + acc[i][0], t.y + acc[i][1],
                        t.z + acc[i][2], t.w + acc[i][3]);
      }
    } else if (w == 0) {
      #pragma unroll
      for (int i = 0; i < 8; ++i) {
        float4 t = *reinterpret_cast<const float4*>(&pB[i][c0]);
        *reinterpret_cast<float4*>(&pB[i][c0]) =
            make_float4(t.x + acc[i][0], t.y + acc[i][1],
                        t.z + acc[i][2], t.w + acc[i][3]);
      }
    }
    __syncthreads();                          // (1b) partials complete
    // stage 3: all waves finalize rows fr0, fr0+1 (params from LDS)
    {
      float4 bb4  = *reinterpret_cast<const float4*>(&sPar[0][c0]);
      float4 wa04 = *reinterpret_cast<const float4*>(&sPar[1][c0]);
      float4 wa14 = *reinterpret_cast<const float4*>(&sPar[2][c0]);
      float4 wa24 = *reinterpret_cast<const float4*>(&sPar[3][c0]);
      float4 wrb4 = *reinterpret_cast<const float4*>(&sPar[4][c0]);
      float bn[2][4];
      #pragma unroll
      for (int rr = 0; rr < 2; ++rr) {
        int r = fr0 + rr;
        float4 a = *reinterpret_cast<const float4*>(&pA[r][c0]);
        float4 b = *reinterpret_cast<const float4*>(&pB[r][c0]);
        float aD = sAD[ph][r], a0 = sA0[ph][r], a1 = sA1[ph][r];
        float t0 = (a.x + b.x) + bb4.x + aD * wa04.x + a0 * wa14.x + a1 * wa24.x;
        float t1 = (a.y + b.y) + bb4.y + aD * wa04.y + a0 * wa14.y + a1 * wa24.y;
        float t2 = (a.z + b.z) + bb4.z + aD * wa04.z + a0 * wa14.z + a1 * wa24.z;
        float t3 = (a.w + b.w) + bb4.w + aD * wa04.w + a0 * wa14.w + a1 * wa24.w;
        bn[rr][0] = tanhf(t0);
        bn[rr][1] = tanhf(t1);
        bn[rr][2] = tanhf(t2);
        bn[rr][3] = tanhf(t3);
        rsum[rr] = fmaf(bn[rr][0], wrb4.x, rsum[rr]);
        rsum[rr] = fmaf(bn[rr][1], wrb4.y, rsum[rr]);
        rsum[rr] = fmaf(bn[rr][2], wrb4.z, rsum[rr]);
        rsum[rr] = fmaf(bn[rr][3], wrb4.w, rsum[rr]);
      }
      // write b' back: float2 (rows fr0, fr0+1) per col
      #pragma unroll
      for (int j = 0; j < 4; ++j)
        *reinterpret_cast<float2*>(&sBc[(c0 + j) * kSB + fr0]) =
            make_float2(bn[0][j], bn[1][j]);
    }
    __syncthreads();                          // (2) new belief visible

    // ---- s partials: 8 rows x 1 z over this wave's 64 k, Ws in regs ----
    float sa[8] = {0,0,0,0,0,0,0,0};
    #pragma unroll
    for (int k = 0; k < 64; ++k) {
      float4 b0 = *reinterpret_cast<const float4*>(bKb + k * kSB);
      float4 b1 = *reinterpret_cast<const float4*>(bKb + k * kSB + 4);
      float wv = wsr[k];
      sa[0] = fmaf(b0.x, wv, sa[0]);
      sa[1] = fmaf(b0.y, wv, sa[1]);
      sa[2] = fmaf(b0.z, wv, sa[2]);
      sa[3] = fmaf(b0.w, wv, sa[3]);
      sa[4] = fmaf(b1.x, wv, sa[4]);
      sa[5] = fmaf(b1.y, wv, sa[5]);
      sa[6] = fmaf(b1.z, wv, sa[6]);
      sa[7] = fmaf(b1.w, wv, sa[7]);
    }
    if (w == 2) {
      #pragma unroll
      for (int i = 0; i < 8; ++i) sA_[i][lane] = sa[i];
    } else if (w == 3) {
      #pragma unroll
      for (int i = 0; i < 8; ++i) sB_[i][lane] = sa[i];
    }
    __syncthreads();                          // (3a) SA,SB written
    if (w == 1) {
      #pragma unroll
      for (int i = 0; i < 8; ++i) sA_[i][lane] += sa[i];
    } else if (w == 0) {
      #pragma unroll
      for (int i = 0; i < 8; ++i) sB_[i][lane] += sa[i];
    }
    __syncthreads();                          // (3b) s-partials complete
    #pragma unroll
    for (int rr = 0; rr < 2; ++rr) {
      int r = fr0 + rr;
      float t = (sA_[r][lane] + sB_[r][lane]) + bsv;
      float sv = tanhf(t);
      ssum[rr] = fmaf(sv, wrsv, ssum[rr]);
    }
    // next step's A/B writes are >= 2 barriers after this step's reads.
  }

  // final: wave w owns rows fr0, fr0+1; reduce over 64 lanes, lane 0 writes.
  #pragma unroll
  for (int rr = 0; rr < 2; ++rr) {
    float v = rsum[rr] + ssum[rr];
    v += __shfl_xor(v, 1, 64);
    v += __shfl_xor(v, 2, 64);
    v += __shfl_xor(v, 4, 64);
    v += __shfl_xor(v, 8, 64);
    v += __shfl_xor(v, 16, 64);
    v += __shfl_xor(v, 32, 64);
    if (lane == 0) ret[row0 + fr0 + rr] = v;
  }
}

// ---------------- per-batch top-k + statistics -----------------------------
__global__ __launch_bounds__(256) void k_topk_stats(
    const float* __restrict__ ret, const float* __restrict__ discA,
    const float* __restrict__ contA, float* __restrict__ freq,
    float* __restrict__ lfreq, float* __restrict__ meanv,
    float* __restrict__ stdv) {
  __shared__ float rv[kCand];
  __shared__ int selc[kTopK];
  __shared__ int hist[kTools];
  const int b = blockIdx.x, tid = threadIdx.x;
  for (int i = tid; i < kCand; i += 256) rv[i] = ret[b * kCand + i];
  __syncthreads();
  for (int c = tid; c < kCand; c += 256) {
    float v = rv[c];
    int rank = 0;
    for (int o = 0; o < kCand; ++o) {
      float vo = rv[o];
      rank += ((vo > v) || (vo == v && o < c)) ? 1 : 0;
    }
    if (rank < kTopK) selc[rank] = c;
  }
  __syncthreads();
  for (int ph = 0; ph < kPH; ++ph) {
    if (tid < kTools) hist[tid] = 0;
    __syncthreads();
    if (tid < kTopK) {
      int c = selc[tid];
      int idx = ph * kRT + b * kCand + c;
      int d = (int)discA[idx];
      atomicAdd(&hist[d], 1);
      float c0 = contA[idx * 2 + 0];
      float c1 = contA[idx * 2 + 1];
      float s0 = c0, s1 = c1;
      #pragma unroll
      for (int sh = 1; sh < 64; sh <<= 1) {
        s0 += __shfl_xor(s0, sh, 64);
        s1 += __shfl_xor(s1, sh, 64);
      }
      float m0 = s0 * (1.0f / 64.0f);
      float m1 = s1 * (1.0f / 64.0f);
      float d0 = c0 - m0, d1 = c1 - m1;
      float q0 = d0 * d0, q1 = d1 * d1;
      #pragma unroll
      for (int sh = 1; sh < 64; sh <<= 1) {
        q0 += __shfl_xor(q0, sh, 64);
        q1 += __shfl_xor(q1, sh, 64);
      }
      if (tid == 0) {
        int o = (ph * kB + b) * 2;
        meanv[o + 0] = m0;
        meanv[o + 1] = m1;
        stdv[o + 0] = sqrtf(q0 * (1.0f / 64.0f));
        stdv[o + 1] = sqrtf(q1 * (1.0f / 64.0f));
      }
    }
    __syncthreads();
    if (tid < kTools) {
      float fq = (float)(hist[tid] + 1) / 100.0f;
      int o = (ph * kB + b) * kTools + tid;
      freq[o] = fq;
      lfreq[o] = (float)log((double)fq);
    }
    __syncthreads();
  }
}

// ---------------- final output ---------------------------------------------
__global__ void k_final(const float* __restrict__ freq,
                        const float* __restrict__ meanv,
                        float* __restrict__ out) {
  int b = threadIdx.x;
  if (b < kB) {
    const float* f = freq + b * kTools;   // ph = 0
    int best = 0; float bv = f[0];
    for (int t = 1; t < kTools; ++t)
      if (f[t] > bv) { bv = f[t]; best = t; }
    out[b * 3 + 0] = (float)best;
    out[b * 3 + 1] = meanv[b * 2 + 0];
    out[b * 3 + 2] = meanv[b * 2 + 1];
  }
}

extern "C" void kernel_launch(void* const* d_in, const int* in_sizes, int n_in,
                              void* d_out, int out_size, void* d_ws, size_t ws_size,
                              hipStream_t stream) {
  (void)in_sizes; (void)n_in; (void)out_size; (void)ws_size;
  const float* belief = (const float*)d_in[0];
  const float* Wb  = (const float*)d_in[2];
  const float* Wa  = (const float*)d_in[3];
  const float* bb  = (const float*)d_in[4];
  const float* Ws  = (const float*)d_in[5];
  const float* bs  = (const float*)d_in[6];
  const float* wrb = (const float*)d_in[7];
  const float* wrs = (const float*)d_in[8];
  float* out = (float*)d_out;

  float* w = (float*)d_ws;
  float* discA = w;                          // PH*RT
  float* contA = discA + kPH * kRT;          // PH*RT*2
  float* ret   = contA + kPH * kRT * 2;      // RT
  float* freq  = ret + kRT;                  // PH*B*NTOOLS
  float* lfreq = freq + kPH * kB * kTools;   // PH*B*NTOOLS
  float* meanv = lfreq + kPH * kB * kTools;  // PH*B*2
  float* stdv  = meanv + kPH * kB * 2;       // PH*B*2

  uint32_t key0 = 0u, key1 = 42u;            // jax.random.key(42)
  for (int it = 0; it < 3; ++it) {
    uint32_t ks[3][2];
    host_split3(key0, key1, ks);
    int it0 = (it == 0) ? 1 : 0;
    k_sample_disc<<<dim3((kCand * kPH * kB + 255) / 256), dim3(256), 0, stream>>>(
        ks[0][0], ks[0][1], lfreq, discA, it0);
    k_sample_cont<<<dim3((kContTotal + 255) / 256), dim3(256), 0, stream>>>(
        ks[1][0], ks[1][1], meanv, stdv, contA, it0);
    k_rollout<<<dim3(kRT / kRowsB), dim3(256), 0, stream>>>(
        belief, discA, contA, Wb, Wa, bb, Ws, bs, wrb, wrs, ret);
    k_topk_stats<<<dim3(kB), dim3(256), 0, stream>>>(
        ret, discA, contA, freq, lfreq, meanv, stdv);
    key0 = ks[2][0]; key1 = ks[2][1];
  }
  k_final<<<dim3(1), dim3(64), 0, stream>>>(freq, meanv, out);
}